// Round 11
// baseline (334.768 us; speedup 1.0000x reference)
//
#include <hip/hip_runtime.h>
#include <stdint.h>

#define HEADS 8
#define DH    32
#define BSZ   8
#define HALO  3
#define WIN   14
#define NKEY  196
#define CIN   256
#define IMG   128
#define HWPIX 16384
#define MQKV  768         // 8 heads x (q32 + k32 + v32), head-blocked
#define SCALE 0.17677669529663689f  // 32^-0.5

#define KS_STRIDE 36      // shorts, 72 B rows (8B aligned, l15*18dw: 16 distinct banks)
#define VT_STRIDE 228     // shorts (114 dw; holds 224 padded keys)
#define PQ_STRIDE 112     // shorts (exactly 7 tiles x 16; keeps LDS at 13 x 4KiB pages)
#define QB_STRIDE 64      // shorts; rows bank-aliased, fixed by per-row rotation rot=(q&7)*4

#define BST_STRIDE 264    // shorts per Bst pixel row (132 dw == 4 mod 32: 2-way reads)

typedef short bf16x8 __attribute__((ext_vector_type(8)));
typedef short bf16x4 __attribute__((ext_vector_type(4)));
typedef float f32x4  __attribute__((ext_vector_type(4)));
typedef unsigned short u16x4 __attribute__((ext_vector_type(4)));
typedef unsigned short u16x8 __attribute__((ext_vector_type(8)));

#define AS1 __attribute__((address_space(1)))
#define AS3 __attribute__((address_space(3)))

__device__ __forceinline__ float bf2f(unsigned short s){ return __uint_as_float(((unsigned int)s) << 16); }
__device__ __forceinline__ unsigned short f2bf(float f){        // RNE
  unsigned int u = __float_as_uint(f);
  u += 0x7fffu + ((u >> 16) & 1u);
  return (unsigned short)(u >> 16);
}

// 8-short fragment from two 8B-aligned LDS halves
__device__ __forceinline__ bf16x8 ld2(const unsigned short* p) {
  bf16x4 a = *(const bf16x4*)p;
  bf16x4 b = *(const bf16x4*)(p + 4);
  bf16x8 r;
  r[0]=a[0]; r[1]=a[1]; r[2]=a[2]; r[3]=a[3];
  r[4]=b[0]; r[5]=b[1]; r[6]=b[2]; r[7]=b[3];
  return r;
}

__device__ __forceinline__ void st_bf4(unsigned short* p, f32x4 c) {
  ushort4 o;
  o.x = f2bf(c[0]); o.y = f2bf(c[1]); o.z = f2bf(c[2]); o.w = f2bf(c[3]);
  *(ushort4*)p = o;
}

// ---------------------------------------------------------------------------
// W fp32 -> bf16, head-blocked rows: m = h*96 + d; d<32 -> wq[h*32+d],
// d in [32,96) -> wkv[h*64 + d-32].
// ---------------------------------------------------------------------------
__global__ void convw_kernel(const float* __restrict__ wq,
                             const float* __restrict__ wkv,
                             unsigned short* __restrict__ Wb)
{
  int idx = blockIdx.x * 256 + threadIdx.x;      // 768 rows x 64 float4
  int m = idx >> 6, c4 = idx & 63;
  int h = m / 96, d = m - h * 96;
  const float* src = (d < 32) ? wq  + (size_t)(h * 32 + d) * CIN
                              : wkv + (size_t)(h * 64 + d - 32) * CIN;
  float4 v = *(const float4*)(src + c4 * 4);
  ushort4 o;
  o.x = f2bf(v.x); o.y = f2bf(v.y); o.z = f2bf(v.z); o.w = f2bf(v.w);
  *(ushort4*)(Wb + (size_t)m * CIN + c4 * 4) = o;
}

// ---------------------------------------------------------------------------
// rel tables -> bf16 [64][32]: rows 0..26 hrel, 27..31 zero, 32..58 wrel, 59..63 zero
// ---------------------------------------------------------------------------
__global__ void convrel_kernel(const float* __restrict__ hrel,
                               const float* __restrict__ wrel,
                               unsigned short* __restrict__ relb)
{
  int idx = blockIdx.x * 256 + threadIdx.x;      // 2048
  int r = idx >> 5, c = idx & 31;
  float v = 0.f;
  if (r < 27) v = hrel[r * 32 + c];
  else if (r >= 32 && r < 59) v = wrel[(r - 32) * 32 + c];
  relb[idx] = f2bf(v);
}

// ---------------------------------------------------------------------------
// Phase 1 (fused): projection GEMM reading x f32 directly.
// r11: A fragments read DIRECTLY from global W (393KB, L2-resident constant —
// every block reads the same data; 64B-segment coalescing, same pattern as
// attn's qf). Removes the As staging and ALL K-loop barriers: 60 -> 13
// barrier drains per block (the r9 structure's dominant stall).
// One block = one 64-pixel tile; Bst [64pix][256cin] staged ONCE; mt=0..5
// m-tiles; per-mt swizzled-E coalesced store (r8-proven, short-family).
// LDS: Bst 33792 + E 16384 = 50176 B = 13 x 4KiB pages -> 3 blocks/CU.
// ---------------------------------------------------------------------------
__global__ __launch_bounds__(256, 3)
void projx_kernel(const float* __restrict__ x,            // chunk base [bl][256][16384] f32
                  const unsigned short* __restrict__ Wb,  // [768][256]
                  unsigned short* __restrict__ qkv)       // [chunk*16384][768]
{
  __shared__ unsigned short Bst[64 * BST_STRIDE];  // 33792 B [pix][256cin] (padded rows)
  __shared__ unsigned short E[128 * 64];           // 16384 B epilogue transpose tile

  const int tid = threadIdx.x;
  const int w = tid >> 6, lane = tid & 63;
  const int g16 = lane >> 4, l15 = lane & 15;
  const int p0 = blockIdx.x * 64;
  const int bl = blockIdx.y;
  const int wm = w >> 1, wn = w & 1;
  const float* xin = x + (size_t)bl * CIN * HWPIX;

  // ---- stage B: x[cin][pix] f32 -> Bst[pix][cin] bf16 (convx T-pattern) ----
  for (int idx = tid; idx < 2048; idx += 256) {
    int cp = idx >> 4, f = idx & 15;
    const float* r0 = xin + (size_t)(2 * cp) * HWPIX + p0 + f * 4;
    float4 a = *(const float4*)r0;
    float4 b = *(const float4*)(r0 + HWPIX);
    unsigned short* bp = Bst + (f * 4) * BST_STRIDE + cp * 2;
    ushort2 o0_, o1_, o2_, o3_;
    o0_.x = f2bf(a.x); o0_.y = f2bf(b.x);
    o1_.x = f2bf(a.y); o1_.y = f2bf(b.y);
    o2_.x = f2bf(a.z); o2_.y = f2bf(b.z);
    o3_.x = f2bf(a.w); o3_.y = f2bf(b.w);
    *(ushort2*)(bp                 ) = o0_;
    *(ushort2*)(bp + BST_STRIDE    ) = o1_;
    *(ushort2*)(bp + BST_STRIDE * 2) = o2_;
    *(ushort2*)(bp + BST_STRIDE * 3) = o3_;
  }
  __syncthreads();

  // ---- m-tile loop: all 6 output tiles from the resident B ----
  for (int mt = 0; mt < 6; ++mt) {
    const int m0 = mt * 128;
    // this wave's 64 W-rows for the whole mt (wm half of the 128-row tile)
    const unsigned short* Wm = Wb + (size_t)(m0 + wm * 64) * CIN;

    f32x4 acc[4][2];
    #pragma unroll
    for (int i = 0; i < 4; ++i)
      #pragma unroll
      for (int j = 0; j < 2; ++j) acc[i][j] = (f32x4){0.f,0.f,0.f,0.f};

    #pragma unroll
    for (int kk = 0; kk < 4; ++kk) {
      const int k0 = kk * 64;
      #pragma unroll
      for (int kh = 0; kh < 2; ++kh) {
        bf16x8 af[4], bfr[2];
        #pragma unroll
        for (int t = 0; t < 4; ++t)
          af[t] = *(const bf16x8*)(Wm + (size_t)(t*16 + l15) * CIN + k0 + kh*32 + g16*8);
        #pragma unroll
        for (int t = 0; t < 2; ++t)
          bfr[t] = *(const bf16x8*)(Bst + (wn*32 + t*16 + l15)*BST_STRIDE + k0 + kh*32 + g16*8);
        #pragma unroll
        for (int tm = 0; tm < 4; ++tm)
          #pragma unroll
          for (int tn = 0; tn < 2; ++tn)
            acc[tm][tn] = __builtin_amdgcn_mfma_f32_16x16x32_bf16(
                            af[tm], bfr[tn], acc[tm][tn], 0, 0, 0);
      }
    }

    // ---- epilogue for this mt: acc -> E (swizzled) -> coalesced global ----
    // E byte addr: pix*256 + ((ch*2) ^ ((pix&7)<<4)); write key l15&7 == read
    // key pl&7 per pixel (r8-proven). Short-family on both sides.
    #pragma unroll
    for (int tm = 0; tm < 4; ++tm) {
      int ch = wm*64 + tm*16 + g16*4;
      #pragma unroll
      for (int tn = 0; tn < 2; ++tn) {
        int pix = wn*32 + tn*16 + l15;
        unsigned int boff = (unsigned)(pix*256 + ((ch*2) ^ ((l15 & 7) << 4)));
        st_bf4((unsigned short*)((char*)E + boff), acc[tm][tn]);
      }
    }
    __syncthreads();
    {
      unsigned short* qrow = qkv + ((size_t)bl * HWPIX + p0) * MQKV + m0;
      #pragma unroll
      for (int r = 0; r < 4; ++r) {
        int pl = w*16 + r*4 + g16;               // 0..63, bijective over threads x r
        unsigned int boff = (unsigned)(pl*256 + ((l15*16) ^ ((pl & 7) << 4)));
        u16x8 vv = *(const u16x8*)((const char*)E + boff);
        *(u16x8*)(qrow + (size_t)pl * MQKV + l15*8) = vv;
      }
    }
    __syncthreads();                             // E reads done before next mt writes
  }
}

// ---------------------------------------------------------------------------
// Phase 2: fused halo attention, MFMA bf16.  (r9 code verbatim — measured
// 100 µs; r10's relb-direct + pointer-bump staging regressed to 126 and is
// reverted.)
// LDS total 53248 B = 13 x 4KiB pages -> 3 blocks/CU (4KiB LDS granularity).
// Key space padded to 224 = 14 ky-tiles x 16 (kx 14..15 zero).
// ---------------------------------------------------------------------------
__global__ __launch_bounds__(256, 3)
void attn_kernel(const unsigned short* __restrict__ qkv,  // chunk base
                 const unsigned short* __restrict__ relb, // [64][32] bf16
                 float* __restrict__ out,                 // [4][256][128][128]
                 int b0)
{
  __shared__ unsigned short Ks[224 * KS_STRIDE];   // 16128 B [ky*16+kx][dh]
  __shared__ unsigned short Vt[32 * VT_STRIDE];    // 14592 B [dh][ky*16+kx]
  __shared__ unsigned short Pq[64 * PQ_STRIDE];    // 14336 B [q][key-in-half] (first 4KB = relb transient)
  __shared__ unsigned short QB[64 * QB_STRIDE];    //  8192 B [q][t_h 0..31 | t_w 32..63] (rotated)

  const int tid = threadIdx.x;
  const int by = blockIdx.x >> 4, bx = blockIdx.x & 15;
  const int hd = blockIdx.y, bb = blockIdx.z;
  const size_t pixbase = (size_t)bb * HWPIX;

  const int w = tid >> 6, lane = tid & 63;
  const int g16 = lane >> 4, l15 = lane & 15;
  const int q = w * 16 + l15;
  const int qy = q >> 3, qx = q & 7;
  const int gy = by * BSZ + qy, gx = bx * BSZ + qx;
  const int rot = qx * 4;                          // per-row bank rotation

  // own q fragment (B-operand for both bias and QK MFMAs)
  bf16x8 qf = *(const bf16x8*)(qkv + (pixbase + (size_t)gy * IMG + gx) * MQKV + hd * 96 + g16 * 8);

  // relb -> Pq[0..2047]
  *(uint4*)(Pq + tid * 8) = *(const uint4*)(relb + tid * 8);

  // stage K (rows, b64 pairs) and V (transposed scatter) over padded key space.
  // 224*8 / 256 = 7 exact iterations; pad/OOB keys write zeros (covers all LDS).
  for (int idx = tid; idx < 224 * 8; idx += 256) {
    int key = idx >> 3, part = idx & 7;
    int ky = key >> 4, kx = key & 15;
    int sy = by * BSZ - HALO + ky, sx = bx * BSZ - HALO + kx;
    uint4 val = make_uint4(0,0,0,0);
    if (kx < WIN && (unsigned)sy < (unsigned)IMG && (unsigned)sx < (unsigned)IMG)
      val = *(const uint4*)(qkv + (pixbase + sy * IMG + sx) * MQKV + hd * 96 + 32 + part * 8);
    if (part < 4) {
      unsigned short* kp = Ks + key * KS_STRIDE + part * 8;
      *(unsigned long long*)(kp    ) = (unsigned long long)val.x | ((unsigned long long)val.y << 32);
      *(unsigned long long*)(kp + 4) = (unsigned long long)val.z | ((unsigned long long)val.w << 32);
    } else {
      int dh0 = (part - 4) * 8;
      unsigned int u[4] = {val.x, val.y, val.z, val.w};
      #pragma unroll
      for (int e = 0; e < 4; ++e) {
        Vt[(dh0 + 2*e    ) * VT_STRIDE + key] = (unsigned short)(u[e] & 0xffffu);
        Vt[(dh0 + 2*e + 1) * VT_STRIDE + key] = (unsigned short)(u[e] >> 16);
      }
    }
  }
  __syncthreads();

  // ---- bias via MFMA: C[t][q] = rel[t] . q ----
  {
    const unsigned short* Hb = Pq;
    const unsigned short* Wr = Pq + 1024;
    bf16x8 ah0 = *(const bf16x8*)(Hb + l15 * 32 + g16 * 8);
    bf16x8 ah1 = *(const bf16x8*)(Hb + (16 + l15) * 32 + g16 * 8);
    bf16x8 aw0 = *(const bf16x8*)(Wr + l15 * 32 + g16 * 8);
    bf16x8 aw1 = *(const bf16x8*)(Wr + (16 + l15) * 32 + g16 * 8);
    f32x4 z = (f32x4){0.f,0.f,0.f,0.f};
    f32x4 ch0 = __builtin_amdgcn_mfma_f32_16x16x32_bf16(ah0, qf, z, 0, 0, 0);
    f32x4 ch1 = __builtin_amdgcn_mfma_f32_16x16x32_bf16(ah1, qf, z, 0, 0, 0);
    f32x4 cw0 = __builtin_amdgcn_mfma_f32_16x16x32_bf16(aw0, qf, z, 0, 0, 0);
    f32x4 cw1 = __builtin_amdgcn_mfma_f32_16x16x32_bf16(aw1, qf, z, 0, 0, 0);
    unsigned short* QBq = QB + q * QB_STRIDE;
    st_bf4(QBq +      (( 0 + g16 * 4 + rot) & 31), ch0);
    st_bf4(QBq +      ((16 + g16 * 4 + rot) & 31), ch1);
    st_bf4(QBq + 32 + (( 0 + g16 * 4 + rot) & 31), cw0);
    st_bf4(QBq + 32 + ((16 + g16 * 4 + rot) & 31), cw1);
  }
  __syncthreads();   // all waves done reading relb region before Pq P-writes

  const unsigned short* QBq = QB + q * QB_STRIDE;
  unsigned short* Prow = Pq + q * PQ_STRIDE;

  const float LOG2E = 1.4426950408889634f;
  const float SL2E  = SCALE * LOG2E;

  // loop-invariant w-bias (x log2e); pad kx>=14 -> -1e30 masks via exp2->0
  float bw2[4];
  #pragma unroll
  for (int i = 0; i < 4; ++i) {
    int kx = g16 * 4 + i;
    bw2[i] = (kx < WIN) ? bf2f(QBq[32 + ((kx - qx + 13 + rot) & 31)]) * LOG2E : -1e30f;
  }
  const int hbase = 13 - qy + rot;                 // h-region read base (rotated)

  float lsum = 0.f;
  f32x4 o0 = (f32x4){0.f,0.f,0.f,0.f}, o1 = (f32x4){0.f,0.f,0.f,0.f};
  const f32x4 z = (f32x4){0.f,0.f,0.f,0.f};

  #pragma unroll
  for (int half = 0; half < 2; ++half) {
    #pragma unroll
    for (int u = 0; u < 7; ++u) {
      const int nt = half * 7 + u;                 // == ky of this tile
      bf16x8 kf = ld2(Ks + (nt * 16 + l15) * KS_STRIDE + g16 * 8);
      f32x4 c = __builtin_amdgcn_mfma_f32_16x16x32_bf16(kf, qf, z, 0, 0, 0);
      float bh2 = bf2f(QBq[(nt + hbase) & 31]) * LOG2E; // per-tile-constant h-bias
      float p0 = exp2f(fmaf(c[0], SL2E, bh2 + bw2[0]));
      float p1 = exp2f(fmaf(c[1], SL2E, bh2 + bw2[1]));
      float p2 = exp2f(fmaf(c[2], SL2E, bh2 + bw2[2]));
      float p3 = exp2f(fmaf(c[3], SL2E, bh2 + bw2[3]));
      lsum += (p0 + p1) + (p2 + p3);
      unsigned int plo, phi;
      asm("v_cvt_pk_bf16_f32 %0, %1, %2" : "=v"(plo) : "v"(p0), "v"(p1));
      asm("v_cvt_pk_bf16_f32 %0, %1, %2" : "=v"(phi) : "v"(p2), "v"(p3));
      union { unsigned int u32[2]; u16x4 v; } pk_;
      pk_.u32[0] = plo; pk_.u32[1] = phi;
      *(u16x4*)(Prow + u * 16 + g16 * 4) = pk_.v;  // ushort-typed store (aliases pf loads)
    }
    asm volatile("" ::: "memory");                 // order P-writes before pf reads
    #pragma unroll
    for (int cc = 0; cc < 4; ++cc) {
      bf16x8 pf = (bf16x8){0,0,0,0,0,0,0,0};
      const bool masked = (cc == 3);               // last 16 keys of half only
      if (!masked || g16 < 2)
        pf = *(const bf16x8*)(Prow + cc * 32 + g16 * 8);
      int vcol = half * 112 + cc * 32 + g16 * 8;
      if (masked && g16 >= 2) vcol = 0;            // pf==0; keep read in-bounds
      bf16x8 v0 = ld2(Vt + l15 * VT_STRIDE + vcol);
      bf16x8 v1 = ld2(Vt + (16 + l15) * VT_STRIDE + vcol);
      o0 = __builtin_amdgcn_mfma_f32_16x16x32_bf16(v0, pf, o0, 0, 0, 0);
      o1 = __builtin_amdgcn_mfma_f32_16x16x32_bf16(v1, pf, o1, 0, 0, 0);
    }
  }

  lsum += __shfl_xor(lsum, 16);
  lsum += __shfl_xor(lsum, 32);
  float inv = 1.f / lsum;

  float* ob = out + (((size_t)(b0 + bb) * 256 + hd * DH) * HWPIX) + (size_t)gy * IMG + gx;
  #pragma unroll
  for (int i = 0; i < 4; ++i) {
    int dh0 = g16 * 4 + i;
    ob[(size_t)dh0 * HWPIX]        = o0[i] * inv;
    ob[(size_t)(dh0 + 16) * HWPIX] = o1[i] * inv;
  }
}

// ---------------------------------------------------------------------------
extern "C" void kernel_launch(void* const* d_in, const int* in_sizes, int n_in,
                              void* d_out, int out_size, void* d_ws, size_t ws_size,
                              hipStream_t stream)
{
  (void)in_sizes; (void)n_in; (void)out_size;
  const float* x    = (const float*)d_in[0];
  const float* wq   = (const float*)d_in[1];
  const float* wkv  = (const float*)d_in[2];
  const float* hrel = (const float*)d_in[3];
  const float* wrel = (const float*)d_in[4];
  float* out = (float*)d_out;

  const size_t wb_bytes   = (size_t)MQKV * CIN * 2;      // 393216
  const size_t relb_bytes = 4096;
  const size_t qkv_per_b  = (size_t)HWPIX * MQKV * 2;    // 25.2 MB
  const int chunk = (ws_size >= wb_bytes + relb_bytes + 4 * qkv_per_b) ? 4 : 1;

  unsigned short* Wb   = (unsigned short*)d_ws;
  unsigned short* relb = (unsigned short*)((char*)d_ws + wb_bytes);
  unsigned short* qkv  = (unsigned short*)((char*)d_ws + wb_bytes + relb_bytes);

  convw_kernel<<<192, 256, 0, stream>>>(wq, wkv, Wb);
  convrel_kernel<<<8, 256, 0, stream>>>(hrel, wrel, relb);

  for (int b0 = 0; b0 < 4; b0 += chunk) {
    projx_kernel<<<dim3(256, chunk), 256, 0, stream>>>(x + (size_t)b0 * CIN * HWPIX, Wb, qkv);
    attn_kernel<<<dim3(256, HEADS, chunk), 256, 0, stream>>>(qkv, relb, out, b0);
  }
}

// Round 12
// 247.831 us; speedup vs baseline: 1.3508x; 1.3508x over previous
//
#include <hip/hip_runtime.h>
#include <stdint.h>

#define HEADS 8
#define DH    32
#define BSZ   8
#define HALO  3
#define WIN   14
#define NKEY  196
#define CIN   256
#define IMG   128
#define HWPIX 16384
#define MQKV  768         // 8 heads x (q32 + k32 + v32), head-blocked
#define SCALE 0.17677669529663689f  // 32^-0.5

#define KS_STRIDE 36      // shorts, 72 B rows (8B aligned, l15*18dw: 16 distinct banks)
#define VT_STRIDE 228     // shorts (114 dw; holds 224 padded keys)
#define PQ_STRIDE 112     // shorts (exactly 7 tiles x 16; keeps LDS at 13 x 4KiB pages)
#define QB_STRIDE 64      // shorts; rows bank-aliased, fixed by per-row rotation rot=(q&7)*4

#define BST_STRIDE 264    // shorts per Bst pixel row (132 dw == 4 mod 32: 2-way reads)
#define AS_STRIDE  68     // shorts per As row: 34 dw odd-pair -> af reads ~2-way (64 was 16-way!)

typedef short bf16x8 __attribute__((ext_vector_type(8)));
typedef short bf16x4 __attribute__((ext_vector_type(4)));
typedef float f32x4  __attribute__((ext_vector_type(4)));
typedef unsigned short u16x4 __attribute__((ext_vector_type(4)));
typedef unsigned short u16x8 __attribute__((ext_vector_type(8)));

#define AS1 __attribute__((address_space(1)))
#define AS3 __attribute__((address_space(3)))

__device__ __forceinline__ float bf2f(unsigned short s){ return __uint_as_float(((unsigned int)s) << 16); }
__device__ __forceinline__ unsigned short f2bf(float f){        // RNE
  unsigned int u = __float_as_uint(f);
  u += 0x7fffu + ((u >> 16) & 1u);
  return (unsigned short)(u >> 16);
}

// 8-short fragment from two 8B-aligned LDS halves
__device__ __forceinline__ bf16x8 ld2(const unsigned short* p) {
  bf16x4 a = *(const bf16x4*)p;
  bf16x4 b = *(const bf16x4*)(p + 4);
  bf16x8 r;
  r[0]=a[0]; r[1]=a[1]; r[2]=a[2]; r[3]=a[3];
  r[4]=b[0]; r[5]=b[1]; r[6]=b[2]; r[7]=b[3];
  return r;
}

__device__ __forceinline__ void st_bf4(unsigned short* p, f32x4 c) {
  ushort4 o;
  o.x = f2bf(c[0]); o.y = f2bf(c[1]); o.z = f2bf(c[2]); o.w = f2bf(c[3]);
  *(ushort4*)p = o;
}

// ---------------------------------------------------------------------------
// W fp32 -> bf16, head-blocked rows: m = h*96 + d; d<32 -> wq[h*32+d],
// d in [32,96) -> wkv[h*64 + d-32].
// ---------------------------------------------------------------------------
__global__ void convw_kernel(const float* __restrict__ wq,
                             const float* __restrict__ wkv,
                             unsigned short* __restrict__ Wb)
{
  int idx = blockIdx.x * 256 + threadIdx.x;      // 768 rows x 64 float4
  int m = idx >> 6, c4 = idx & 63;
  int h = m / 96, d = m - h * 96;
  const float* src = (d < 32) ? wq  + (size_t)(h * 32 + d) * CIN
                              : wkv + (size_t)(h * 64 + d - 32) * CIN;
  float4 v = *(const float4*)(src + c4 * 4);
  ushort4 o;
  o.x = f2bf(v.x); o.y = f2bf(v.y); o.z = f2bf(v.z); o.w = f2bf(v.w);
  *(ushort4*)(Wb + (size_t)m * CIN + c4 * 4) = o;
}

// ---------------------------------------------------------------------------
// rel tables -> bf16 [64][32]: rows 0..26 hrel, 27..31 zero, 32..58 wrel, 59..63 zero
// ---------------------------------------------------------------------------
__global__ void convrel_kernel(const float* __restrict__ hrel,
                               const float* __restrict__ wrel,
                               unsigned short* __restrict__ relb)
{
  int idx = blockIdx.x * 256 + threadIdx.x;      // 2048
  int r = idx >> 5, c = idx & 31;
  float v = 0.f;
  if (r < 27) v = hrel[r * 32 + c];
  else if (r >= 32 && r < 59) v = wrel[(r - 32) * 32 + c];
  relb[idx] = f2bf(v);
}

// ---------------------------------------------------------------------------
// Phase 1 (fused): projection GEMM reading x f32 directly.
// r12: A staged via REGISTERS (global bf16x8 -> areg -> ds_write), which
// unlocks two fixes gl_lds16 forbids (wave-uniform dest, m104):
//  (a) As rows padded to 68 shorts — the old 64-short (128B) rows made every
//      af ds_read_b128 a 16-way bank conflict (G4 trap);
//  (b) T14 issue-early/write-late: next tile's A loads issue BEFORE the 16
//      MFMAs of the current tile — L2 latency hides under compute instead of
//      draining at a barrier. (r11's direct-global-A showed the raw latency:
//      VALUBusy 5%, 160 µs. MFMA must eat from LDS; loads must fly early.)
// One block = one 64-pixel tile; Bst [64pix][256cin] staged once; mt=0..5;
// per-mt swizzled-E coalesced store (r8-proven; E reuses As front, 16384B).
// LDS: Bst 33792 + As 17408 = 51200 B = 13 x 4KiB pages -> 3 blocks/CU.
// Type families (r3/r6/r8 rule): all LDS pairs short-family.
// ---------------------------------------------------------------------------
__global__ __launch_bounds__(256, 3)
void projx_kernel(const float* __restrict__ x,            // chunk base [bl][256][16384] f32
                  const unsigned short* __restrict__ Wb,  // [768][256]
                  unsigned short* __restrict__ qkv)       // [chunk*16384][768]
{
  __shared__ unsigned short Bst[64 * BST_STRIDE];  // 33792 B [pix][256cin] (padded rows)
  __shared__ unsigned short As[128 * AS_STRIDE];   // 17408 B A tile (padded); E reuses front

  const int tid = threadIdx.x;
  const int w = tid >> 6, lane = tid & 63;
  const int g16 = lane >> 4, l15 = lane & 15;
  const int p0 = blockIdx.x * 64;
  const int bl = blockIdx.y;
  const int wm = w >> 1, wn = w & 1;
  const float* xin = x + (size_t)bl * CIN * HWPIX;

  const int arow = lane >> 3;            // 0..7 row within this thread's ci-block
  const int acol = (lane & 7) * 8;       // 0..56 col (shorts)

  // issue A loads for (mt=0,kk=0) FIRST — in flight during the Bst staging
  bf16x8 areg[4];
  #pragma unroll
  for (int c = 0; c < 4; ++c) {
    int ci = w * 4 + c;
    areg[c] = *(const bf16x8*)(Wb + (size_t)(ci * 8 + arow) * CIN + acol);
  }

  // ---- stage B: x[cin][pix] f32 -> Bst[pix][cin] bf16 (convx T-pattern) ----
  for (int idx = tid; idx < 2048; idx += 256) {
    int cp = idx >> 4, f = idx & 15;
    const float* r0 = xin + (size_t)(2 * cp) * HWPIX + p0 + f * 4;
    float4 a = *(const float4*)r0;
    float4 b = *(const float4*)(r0 + HWPIX);
    unsigned short* bp = Bst + (f * 4) * BST_STRIDE + cp * 2;
    ushort2 o0_, o1_, o2_, o3_;
    o0_.x = f2bf(a.x); o0_.y = f2bf(b.x);
    o1_.x = f2bf(a.y); o1_.y = f2bf(b.y);
    o2_.x = f2bf(a.z); o2_.y = f2bf(b.z);
    o3_.x = f2bf(a.w); o3_.y = f2bf(b.w);
    *(ushort2*)(bp                 ) = o0_;
    *(ushort2*)(bp + BST_STRIDE    ) = o1_;
    *(ushort2*)(bp + BST_STRIDE * 2) = o2_;
    *(ushort2*)(bp + BST_STRIDE * 3) = o3_;
  }
  __syncthreads();

  // ---- m-tile loop: all 6 output tiles from the resident B ----
  for (int mt = 0; mt < 6; ++mt) {
    f32x4 acc[4][2];
    #pragma unroll
    for (int i = 0; i < 4; ++i)
      #pragma unroll
      for (int j = 0; j < 2; ++j) acc[i][j] = (f32x4){0.f,0.f,0.f,0.f};

    #pragma unroll
    for (int kk = 0; kk < 4; ++kk) {
      // write staged A regs -> As (short-family b128 stores; padded stride)
      #pragma unroll
      for (int c = 0; c < 4; ++c) {
        int ci = w * 4 + c;
        *(bf16x8*)(As + (ci * 8 + arow) * AS_STRIDE + acol) = areg[c];
      }
      __syncthreads();

      // issue NEXT tile's A loads now — they fly during the MFMAs below
      {
        int nit = mt * 4 + kk + 1;
        if (nit < 24) {
          int nm0 = (nit >> 2) * 128, nk0 = (nit & 3) * 64;
          #pragma unroll
          for (int c = 0; c < 4; ++c) {
            int ci = w * 4 + c;
            areg[c] = *(const bf16x8*)(Wb + (size_t)(nm0 + ci * 8 + arow) * CIN + nk0 + acol);
          }
        }
      }

      const int k0 = kk * 64;
      #pragma unroll
      for (int kh = 0; kh < 2; ++kh) {
        bf16x8 af[4], bfr[2];
        #pragma unroll
        for (int t = 0; t < 4; ++t)
          af[t] = *(const bf16x8*)(As + (wm*64 + t*16 + l15) * AS_STRIDE + kh*32 + g16*8);
        #pragma unroll
        for (int t = 0; t < 2; ++t)
          bfr[t] = *(const bf16x8*)(Bst + (wn*32 + t*16 + l15)*BST_STRIDE + k0 + kh*32 + g16*8);
        #pragma unroll
        for (int tm = 0; tm < 4; ++tm)
          #pragma unroll
          for (int tn = 0; tn < 2; ++tn)
            acc[tm][tn] = __builtin_amdgcn_mfma_f32_16x16x32_bf16(
                            af[tm], bfr[tn], acc[tm][tn], 0, 0, 0);
      }
      __syncthreads();                    // As reads done before next kk's write
    }

    // ---- epilogue for this mt: acc -> E (swizzled, front of As) -> coalesced ----
    // E byte addr: pix*256 + ((ch*2) ^ ((pix&7)<<4)); write key l15&7 == read
    // key pl&7 per pixel (r8-proven). Short-family both sides. Max offset 16384.
    const int m0 = mt * 128;
    #pragma unroll
    for (int tm = 0; tm < 4; ++tm) {
      int ch = wm*64 + tm*16 + g16*4;
      #pragma unroll
      for (int tn = 0; tn < 2; ++tn) {
        int pix = wn*32 + tn*16 + l15;
        unsigned int boff = (unsigned)(pix*256 + ((ch*2) ^ ((l15 & 7) << 4)));
        st_bf4((unsigned short*)((char*)As + boff), acc[tm][tn]);
      }
    }
    __syncthreads();
    {
      unsigned short* qrow = qkv + ((size_t)bl * HWPIX + p0) * MQKV + m0;
      #pragma unroll
      for (int r = 0; r < 4; ++r) {
        int pl = w*16 + r*4 + g16;               // 0..63, bijective over threads x r
        unsigned int boff = (unsigned)(pl*256 + ((l15*16) ^ ((pl & 7) << 4)));
        u16x8 vv = *(const u16x8*)((const char*)As + boff);
        *(u16x8*)(qrow + (size_t)pl * MQKV + l15*8) = vv;
      }
    }
    __syncthreads();                             // E reads done before next mt's As writes
  }
}

// ---------------------------------------------------------------------------
// Phase 2: fused halo attention, MFMA bf16.  (r9 code verbatim — measured
// ~100 µs; r10's relb-direct + pointer-bump staging regressed and stays out.)
// LDS total 53248 B = 13 x 4KiB pages -> 3 blocks/CU (4KiB LDS granularity).
// Key space padded to 224 = 14 ky-tiles x 16 (kx 14..15 zero).
// ---------------------------------------------------------------------------
__global__ __launch_bounds__(256, 3)
void attn_kernel(const unsigned short* __restrict__ qkv,  // chunk base
                 const unsigned short* __restrict__ relb, // [64][32] bf16
                 float* __restrict__ out,                 // [4][256][128][128]
                 int b0)
{
  __shared__ unsigned short Ks[224 * KS_STRIDE];   // 16128 B [ky*16+kx][dh]
  __shared__ unsigned short Vt[32 * VT_STRIDE];    // 14592 B [dh][ky*16+kx]
  __shared__ unsigned short Pq[64 * PQ_STRIDE];    // 14336 B [q][key-in-half] (first 4KB = relb transient)
  __shared__ unsigned short QB[64 * QB_STRIDE];    //  8192 B [q][t_h 0..31 | t_w 32..63] (rotated)

  const int tid = threadIdx.x;
  const int by = blockIdx.x >> 4, bx = blockIdx.x & 15;
  const int hd = blockIdx.y, bb = blockIdx.z;
  const size_t pixbase = (size_t)bb * HWPIX;

  const int w = tid >> 6, lane = tid & 63;
  const int g16 = lane >> 4, l15 = lane & 15;
  const int q = w * 16 + l15;
  const int qy = q >> 3, qx = q & 7;
  const int gy = by * BSZ + qy, gx = bx * BSZ + qx;
  const int rot = qx * 4;                          // per-row bank rotation

  // own q fragment (B-operand for both bias and QK MFMAs)
  bf16x8 qf = *(const bf16x8*)(qkv + (pixbase + (size_t)gy * IMG + gx) * MQKV + hd * 96 + g16 * 8);

  // relb -> Pq[0..2047]
  *(uint4*)(Pq + tid * 8) = *(const uint4*)(relb + tid * 8);

  // stage K (rows, b64 pairs) and V (transposed scatter) over padded key space.
  // 224*8 / 256 = 7 exact iterations; pad/OOB keys write zeros (covers all LDS).
  for (int idx = tid; idx < 224 * 8; idx += 256) {
    int key = idx >> 3, part = idx & 7;
    int ky = key >> 4, kx = key & 15;
    int sy = by * BSZ - HALO + ky, sx = bx * BSZ - HALO + kx;
    uint4 val = make_uint4(0,0,0,0);
    if (kx < WIN && (unsigned)sy < (unsigned)IMG && (unsigned)sx < (unsigned)IMG)
      val = *(const uint4*)(qkv + (pixbase + sy * IMG + sx) * MQKV + hd * 96 + 32 + part * 8);
    if (part < 4) {
      unsigned short* kp = Ks + key * KS_STRIDE + part * 8;
      *(unsigned long long*)(kp    ) = (unsigned long long)val.x | ((unsigned long long)val.y << 32);
      *(unsigned long long*)(kp + 4) = (unsigned long long)val.z | ((unsigned long long)val.w << 32);
    } else {
      int dh0 = (part - 4) * 8;
      unsigned int u[4] = {val.x, val.y, val.z, val.w};
      #pragma unroll
      for (int e = 0; e < 4; ++e) {
        Vt[(dh0 + 2*e    ) * VT_STRIDE + key] = (unsigned short)(u[e] & 0xffffu);
        Vt[(dh0 + 2*e + 1) * VT_STRIDE + key] = (unsigned short)(u[e] >> 16);
      }
    }
  }
  __syncthreads();

  // ---- bias via MFMA: C[t][q] = rel[t] . q ----
  {
    const unsigned short* Hb = Pq;
    const unsigned short* Wr = Pq + 1024;
    bf16x8 ah0 = *(const bf16x8*)(Hb + l15 * 32 + g16 * 8);
    bf16x8 ah1 = *(const bf16x8*)(Hb + (16 + l15) * 32 + g16 * 8);
    bf16x8 aw0 = *(const bf16x8*)(Wr + l15 * 32 + g16 * 8);
    bf16x8 aw1 = *(const bf16x8*)(Wr + (16 + l15) * 32 + g16 * 8);
    f32x4 z = (f32x4){0.f,0.f,0.f,0.f};
    f32x4 ch0 = __builtin_amdgcn_mfma_f32_16x16x32_bf16(ah0, qf, z, 0, 0, 0);
    f32x4 ch1 = __builtin_amdgcn_mfma_f32_16x16x32_bf16(ah1, qf, z, 0, 0, 0);
    f32x4 cw0 = __builtin_amdgcn_mfma_f32_16x16x32_bf16(aw0, qf, z, 0, 0, 0);
    f32x4 cw1 = __builtin_amdgcn_mfma_f32_16x16x32_bf16(aw1, qf, z, 0, 0, 0);
    unsigned short* QBq = QB + q * QB_STRIDE;
    st_bf4(QBq +      (( 0 + g16 * 4 + rot) & 31), ch0);
    st_bf4(QBq +      ((16 + g16 * 4 + rot) & 31), ch1);
    st_bf4(QBq + 32 + (( 0 + g16 * 4 + rot) & 31), cw0);
    st_bf4(QBq + 32 + ((16 + g16 * 4 + rot) & 31), cw1);
  }
  __syncthreads();   // all waves done reading relb region before Pq P-writes

  const unsigned short* QBq = QB + q * QB_STRIDE;
  unsigned short* Prow = Pq + q * PQ_STRIDE;

  const float LOG2E = 1.4426950408889634f;
  const float SL2E  = SCALE * LOG2E;

  // loop-invariant w-bias (x log2e); pad kx>=14 -> -1e30 masks via exp2->0
  float bw2[4];
  #pragma unroll
  for (int i = 0; i < 4; ++i) {
    int kx = g16 * 4 + i;
    bw2[i] = (kx < WIN) ? bf2f(QBq[32 + ((kx - qx + 13 + rot) & 31)]) * LOG2E : -1e30f;
  }
  const int hbase = 13 - qy + rot;                 // h-region read base (rotated)

  float lsum = 0.f;
  f32x4 o0 = (f32x4){0.f,0.f,0.f,0.f}, o1 = (f32x4){0.f,0.f,0.f,0.f};
  const f32x4 z = (f32x4){0.f,0.f,0.f,0.f};

  #pragma unroll
  for (int half = 0; half < 2; ++half) {
    #pragma unroll
    for (int u = 0; u < 7; ++u) {
      const int nt = half * 7 + u;                 // == ky of this tile
      bf16x8 kf = ld2(Ks + (nt * 16 + l15) * KS_STRIDE + g16 * 8);
      f32x4 c = __builtin_amdgcn_mfma_f32_16x16x32_bf16(kf, qf, z, 0, 0, 0);
      float bh2 = bf2f(QBq[(nt + hbase) & 31]) * LOG2E; // per-tile-constant h-bias
      float p0 = exp2f(fmaf(c[0], SL2E, bh2 + bw2[0]));
      float p1 = exp2f(fmaf(c[1], SL2E, bh2 + bw2[1]));
      float p2 = exp2f(fmaf(c[2], SL2E, bh2 + bw2[2]));
      float p3 = exp2f(fmaf(c[3], SL2E, bh2 + bw2[3]));
      lsum += (p0 + p1) + (p2 + p3);
      unsigned int plo, phi;
      asm("v_cvt_pk_bf16_f32 %0, %1, %2" : "=v"(plo) : "v"(p0), "v"(p1));
      asm("v_cvt_pk_bf16_f32 %0, %1, %2" : "=v"(phi) : "v"(p2), "v"(p3));
      union { unsigned int u32[2]; u16x4 v; } pk_;
      pk_.u32[0] = plo; pk_.u32[1] = phi;
      *(u16x4*)(Prow + u * 16 + g16 * 4) = pk_.v;  // ushort-typed store (aliases pf loads)
    }
    asm volatile("" ::: "memory");                 // order P-writes before pf reads
    #pragma unroll
    for (int cc = 0; cc < 4; ++cc) {
      bf16x8 pf = (bf16x8){0,0,0,0,0,0,0,0};
      const bool masked = (cc == 3);               // last 16 keys of half only
      if (!masked || g16 < 2)
        pf = *(const bf16x8*)(Prow + cc * 32 + g16 * 8);
      int vcol = half * 112 + cc * 32 + g16 * 8;
      if (masked && g16 >= 2) vcol = 0;            // pf==0; keep read in-bounds
      bf16x8 v0 = ld2(Vt + l15 * VT_STRIDE + vcol);
      bf16x8 v1 = ld2(Vt + (16 + l15) * VT_STRIDE + vcol);
      o0 = __builtin_amdgcn_mfma_f32_16x16x32_bf16(v0, pf, o0, 0, 0, 0);
      o1 = __builtin_amdgcn_mfma_f32_16x16x32_bf16(v1, pf, o1, 0, 0, 0);
    }
  }

  lsum += __shfl_xor(lsum, 16);
  lsum += __shfl_xor(lsum, 32);
  float inv = 1.f / lsum;

  float* ob = out + (((size_t)(b0 + bb) * 256 + hd * DH) * HWPIX) + (size_t)gy * IMG + gx;
  #pragma unroll
  for (int i = 0; i < 4; ++i) {
    int dh0 = g16 * 4 + i;
    ob[(size_t)dh0 * HWPIX]        = o0[i] * inv;
    ob[(size_t)(dh0 + 16) * HWPIX] = o1[i] * inv;
  }
}

// ---------------------------------------------------------------------------
extern "C" void kernel_launch(void* const* d_in, const int* in_sizes, int n_in,
                              void* d_out, int out_size, void* d_ws, size_t ws_size,
                              hipStream_t stream)
{
  (void)in_sizes; (void)n_in; (void)out_size;
  const float* x    = (const float*)d_in[0];
  const float* wq   = (const float*)d_in[1];
  const float* wkv  = (const float*)d_in[2];
  const float* hrel = (const float*)d_in[3];
  const float* wrel = (const float*)d_in[4];
  float* out = (float*)d_out;

  const size_t wb_bytes   = (size_t)MQKV * CIN * 2;      // 393216
  const size_t relb_bytes = 4096;
  const size_t qkv_per_b  = (size_t)HWPIX * MQKV * 2;    // 25.2 MB
  const int chunk = (ws_size >= wb_bytes + relb_bytes + 4 * qkv_per_b) ? 4 : 1;

  unsigned short* Wb   = (unsigned short*)d_ws;
  unsigned short* relb = (unsigned short*)((char*)d_ws + wb_bytes);
  unsigned short* qkv  = (unsigned short*)((char*)d_ws + wb_bytes + relb_bytes);

  convw_kernel<<<192, 256, 0, stream>>>(wq, wkv, Wb);
  convrel_kernel<<<8, 256, 0, stream>>>(hrel, wrel, relb);

  for (int b0 = 0; b0 < 4; b0 += chunk) {
    projx_kernel<<<dim3(256, chunk), 256, 0, stream>>>(x + (size_t)b0 * CIN * HWPIX, Wb, qkv);
    attn_kernel<<<dim3(256, HEADS, chunk), 256, 0, stream>>>(qkv, relb, out, b0);
  }
}

// Round 14
// 246.122 us; speedup vs baseline: 1.3602x; 1.0069x over previous
//
#include <hip/hip_runtime.h>
#include <hip/hip_bf16.h>
#include <stdint.h>

#define HEADS 8
#define DH    32
#define BSZ   8
#define HALO  3
#define WIN   14
#define NKEY  196
#define CIN   256
#define IMG   128
#define HWPIX 16384
#define MQKV  768         // 8 heads x (q32 + k32 + v32), head-blocked
#define SCALE 0.17677669529663689f  // 32^-0.5

#define KS_STRIDE 36      // shorts, 72 B rows (8B aligned, l15*18dw: 16 distinct banks)
#define VT_STRIDE 228     // shorts (114 dw; holds 224 padded keys)
#define PQ_STRIDE 112     // shorts (exactly 7 tiles x 16; keeps LDS at 13 x 4KiB pages)
#define QB_STRIDE 64      // shorts; rows bank-aliased, fixed by per-row rotation rot=(q&7)*4

#define BST_STRIDE 264    // shorts per Bst pixel row (132 dw == 4 mod 32: 2-way reads)
#define AS_STRIDE  68     // shorts per As row: 34 dw odd-pair -> af reads ~2-way (64 was 16-way!)

typedef short bf16x8 __attribute__((ext_vector_type(8)));
typedef short bf16x4 __attribute__((ext_vector_type(4)));
typedef float f32x4  __attribute__((ext_vector_type(4)));
typedef unsigned short u16x4 __attribute__((ext_vector_type(4)));
typedef unsigned short u16x8 __attribute__((ext_vector_type(8)));

#define AS1 __attribute__((address_space(1)))
#define AS3 __attribute__((address_space(3)))

__device__ __forceinline__ float bf2f(unsigned short s){ return __uint_as_float(((unsigned int)s) << 16); }
__device__ __forceinline__ unsigned short f2bf(float f){        // RNE (cold paths only)
  unsigned int u = __float_as_uint(f);
  u += 0x7fffu + ((u >> 16) & 1u);
  return (unsigned short)(u >> 16);
}

// ---- conversion idiom (r3/r6/r13 lesson) ----
// Inline-asm v_cvt_pk reading MFMA (AGPR) outputs miscompiles silently (3x NaN).
// COMPILER casts (__float22bfloat162_rn, RNE) emit cvt_pk AND handle the
// AGPR->VGPR transfer correctly. Use these everywhere; asm cvt_pk only in the
// P-path where inputs are plain VALU values (proven since r4).
__device__ __forceinline__ ushort2 pk2c(float a, float b) {
  __hip_bfloat162 h = __float22bfloat162_rn(make_float2(a, b));
  union { __hip_bfloat162 h2; ushort2 v; } r; r.h2 = h; return r.v;
}
__device__ __forceinline__ void st_bf4c(unsigned short* p, f32x4 c) {
  ushort2 lo = pk2c(c[0], c[1]), hi = pk2c(c[2], c[3]);
  ushort4 o; o.x = lo.x; o.y = lo.y; o.z = hi.x; o.w = hi.y;
  *(ushort4*)p = o;                                 // ushort4 store, same as r12
}

// 8-short fragment from two 8B-aligned LDS halves
__device__ __forceinline__ bf16x8 ld2(const unsigned short* p) {
  bf16x4 a = *(const bf16x4*)p;
  bf16x4 b = *(const bf16x4*)(p + 4);
  bf16x8 r;
  r[0]=a[0]; r[1]=a[1]; r[2]=a[2]; r[3]=a[3];
  r[4]=b[0]; r[5]=b[1]; r[6]=b[2]; r[7]=b[3];
  return r;
}

__device__ __forceinline__ void st_bf4(unsigned short* p, f32x4 c) {  // cold paths
  ushort4 o;
  o.x = f2bf(c[0]); o.y = f2bf(c[1]); o.z = f2bf(c[2]); o.w = f2bf(c[3]);
  *(ushort4*)p = o;
}

// ---------------------------------------------------------------------------
// W fp32 -> bf16, head-blocked rows: m = h*96 + d; d<32 -> wq[h*32+d],
// d in [32,96) -> wkv[h*64 + d-32].
// ---------------------------------------------------------------------------
__global__ void convw_kernel(const float* __restrict__ wq,
                             const float* __restrict__ wkv,
                             unsigned short* __restrict__ Wb)
{
  int idx = blockIdx.x * 256 + threadIdx.x;      // 768 rows x 64 float4
  int m = idx >> 6, c4 = idx & 63;
  int h = m / 96, d = m - h * 96;
  const float* src = (d < 32) ? wq  + (size_t)(h * 32 + d) * CIN
                              : wkv + (size_t)(h * 64 + d - 32) * CIN;
  float4 v = *(const float4*)(src + c4 * 4);
  ushort4 o;
  o.x = f2bf(v.x); o.y = f2bf(v.y); o.z = f2bf(v.z); o.w = f2bf(v.w);
  *(ushort4*)(Wb + (size_t)m * CIN + c4 * 4) = o;
}

// ---------------------------------------------------------------------------
// rel tables -> bf16 [64][32]: rows 0..26 hrel, 27..31 zero, 32..58 wrel, 59..63 zero
// ---------------------------------------------------------------------------
__global__ void convrel_kernel(const float* __restrict__ hrel,
                               const float* __restrict__ wrel,
                               unsigned short* __restrict__ relb)
{
  int idx = blockIdx.x * 256 + threadIdx.x;      // 2048
  int r = idx >> 5, c = idx & 31;
  float v = 0.f;
  if (r < 27) v = hrel[r * 32 + c];
  else if (r >= 32 && r < 59) v = wrel[(r - 32) * 32 + c];
  relb[idx] = f2bf(v);
}

// ---------------------------------------------------------------------------
// Phase 1 (fused): projection GEMM reading x f32 directly.
// r12 structure (reg-staged A, padded As, issue-early loads) + r14: hot
// f32->bf16 conversions via COMPILER casts (pk2c/st_bf4c) — saves the ~4-VALU
// manual RNE per element without the asm-on-AGPR hazard.
// LDS: Bst 33792 + As 17408 = 51200 B = 13 x 4KiB pages -> 3 blocks/CU.
// ---------------------------------------------------------------------------
__global__ __launch_bounds__(256, 3)
void projx_kernel(const float* __restrict__ x,            // chunk base [bl][256][16384] f32
                  const unsigned short* __restrict__ Wb,  // [768][256]
                  unsigned short* __restrict__ qkv)       // [chunk*16384][768]
{
  __shared__ unsigned short Bst[64 * BST_STRIDE];  // 33792 B [pix][256cin] (padded rows)
  __shared__ unsigned short As[128 * AS_STRIDE];   // 17408 B A tile (padded); E reuses front

  const int tid = threadIdx.x;
  const int w = tid >> 6, lane = tid & 63;
  const int g16 = lane >> 4, l15 = lane & 15;
  const int p0 = blockIdx.x * 64;
  const int bl = blockIdx.y;
  const int wm = w >> 1, wn = w & 1;
  const float* xin = x + (size_t)bl * CIN * HWPIX;

  const int arow = lane >> 3;            // 0..7 row within this thread's ci-block
  const int acol = (lane & 7) * 8;       // 0..56 col (shorts)

  // issue A loads for (mt=0,kk=0) FIRST — in flight during the Bst staging
  bf16x8 areg[4];
  #pragma unroll
  for (int c = 0; c < 4; ++c) {
    int ci = w * 4 + c;
    areg[c] = *(const bf16x8*)(Wb + (size_t)(ci * 8 + arow) * CIN + acol);
  }

  // ---- stage B: x[cin][pix] f32 -> Bst[pix][cin] bf16 (convx T-pattern) ----
  for (int idx = tid; idx < 2048; idx += 256) {
    int cp = idx >> 4, f = idx & 15;
    const float* r0 = xin + (size_t)(2 * cp) * HWPIX + p0 + f * 4;
    float4 a = *(const float4*)r0;
    float4 b = *(const float4*)(r0 + HWPIX);
    unsigned short* bp = Bst + (f * 4) * BST_STRIDE + cp * 2;
    *(ushort2*)(bp                 ) = pk2c(a.x, b.x);
    *(ushort2*)(bp + BST_STRIDE    ) = pk2c(a.y, b.y);
    *(ushort2*)(bp + BST_STRIDE * 2) = pk2c(a.z, b.z);
    *(ushort2*)(bp + BST_STRIDE * 3) = pk2c(a.w, b.w);
  }
  __syncthreads();

  // ---- m-tile loop: all 6 output tiles from the resident B ----
  for (int mt = 0; mt < 6; ++mt) {
    f32x4 acc[4][2];
    #pragma unroll
    for (int i = 0; i < 4; ++i)
      #pragma unroll
      for (int j = 0; j < 2; ++j) acc[i][j] = (f32x4){0.f,0.f,0.f,0.f};

    #pragma unroll
    for (int kk = 0; kk < 4; ++kk) {
      // write staged A regs -> As (short-family b128 stores; padded stride)
      #pragma unroll
      for (int c = 0; c < 4; ++c) {
        int ci = w * 4 + c;
        *(bf16x8*)(As + (ci * 8 + arow) * AS_STRIDE + acol) = areg[c];
      }
      __syncthreads();

      // issue NEXT tile's A loads now — they fly during the MFMAs below
      {
        int nit = mt * 4 + kk + 1;
        if (nit < 24) {
          int nm0 = (nit >> 2) * 128, nk0 = (nit & 3) * 64;
          #pragma unroll
          for (int c = 0; c < 4; ++c) {
            int ci = w * 4 + c;
            areg[c] = *(const bf16x8*)(Wb + (size_t)(nm0 + ci * 8 + arow) * CIN + nk0 + acol);
          }
        }
      }

      const int k0 = kk * 64;
      #pragma unroll
      for (int kh = 0; kh < 2; ++kh) {
        bf16x8 af[4], bfr[2];
        #pragma unroll
        for (int t = 0; t < 4; ++t)
          af[t] = *(const bf16x8*)(As + (wm*64 + t*16 + l15) * AS_STRIDE + kh*32 + g16*8);
        #pragma unroll
        for (int t = 0; t < 2; ++t)
          bfr[t] = *(const bf16x8*)(Bst + (wn*32 + t*16 + l15)*BST_STRIDE + k0 + kh*32 + g16*8);
        #pragma unroll
        for (int tm = 0; tm < 4; ++tm)
          #pragma unroll
          for (int tn = 0; tn < 2; ++tn)
            acc[tm][tn] = __builtin_amdgcn_mfma_f32_16x16x32_bf16(
                            af[tm], bfr[tn], acc[tm][tn], 0, 0, 0);
      }
      __syncthreads();                    // As reads done before next kk's write
    }

    // ---- epilogue for this mt: acc -> E (swizzled, front of As) -> coalesced ----
    // E byte addr: pix*256 + ((ch*2) ^ ((pix&7)<<4)); write key l15&7 == read
    // key pl&7 per pixel (r8-proven). Short-family both sides.
    const int m0 = mt * 128;
    #pragma unroll
    for (int tm = 0; tm < 4; ++tm) {
      int ch = wm*64 + tm*16 + g16*4;
      #pragma unroll
      for (int tn = 0; tn < 2; ++tn) {
        int pix = wn*32 + tn*16 + l15;
        unsigned int boff = (unsigned)(pix*256 + ((ch*2) ^ ((l15 & 7) << 4)));
        st_bf4c((unsigned short*)((char*)As + boff), acc[tm][tn]);
      }
    }
    __syncthreads();
    {
      unsigned short* qrow = qkv + ((size_t)bl * HWPIX + p0) * MQKV + m0;
      #pragma unroll
      for (int r = 0; r < 4; ++r) {
        int pl = w*16 + r*4 + g16;               // 0..63, bijective over threads x r
        unsigned int boff = (unsigned)(pl*256 + ((l15*16) ^ ((pl & 7) << 4)));
        u16x8 vv = *(const u16x8*)((const char*)As + boff);
        *(u16x8*)(qrow + (size_t)pl * MQKV + l15*8) = vv;
      }
    }
    __syncthreads();                             // E reads done before next mt's As writes
  }
}

// ---------------------------------------------------------------------------
// Phase 2: fused halo attention, MFMA bf16.  (r9/r12 structure; r14: bias-QB
// stores via compiler-cast st_bf4c — AGPR-safe, saves manual RNE VALU.)
// LDS total 53248 B = 13 x 4KiB pages -> 3 blocks/CU (4KiB LDS granularity).
// Key space padded to 224 = 14 ky-tiles x 16 (kx 14..15 zero).
// ---------------------------------------------------------------------------
__global__ __launch_bounds__(256, 3)
void attn_kernel(const unsigned short* __restrict__ qkv,  // chunk base
                 const unsigned short* __restrict__ relb, // [64][32] bf16
                 float* __restrict__ out,                 // [4][256][128][128]
                 int b0)
{
  __shared__ unsigned short Ks[224 * KS_STRIDE];   // 16128 B [ky*16+kx][dh]
  __shared__ unsigned short Vt[32 * VT_STRIDE];    // 14592 B [dh][ky*16+kx]
  __shared__ unsigned short Pq[64 * PQ_STRIDE];    // 14336 B [q][key-in-half] (first 4KB = relb transient)
  __shared__ unsigned short QB[64 * QB_STRIDE];    //  8192 B [q][t_h 0..31 | t_w 32..63] (rotated)

  const int tid = threadIdx.x;
  const int by = blockIdx.x >> 4, bx = blockIdx.x & 15;
  const int hd = blockIdx.y, bb = blockIdx.z;
  const size_t pixbase = (size_t)bb * HWPIX;

  const int w = tid >> 6, lane = tid & 63;
  const int g16 = lane >> 4, l15 = lane & 15;
  const int q = w * 16 + l15;
  const int qy = q >> 3, qx = q & 7;
  const int gy = by * BSZ + qy, gx = bx * BSZ + qx;
  const int rot = qx * 4;                          // per-row bank rotation

  // own q fragment (B-operand for both bias and QK MFMAs)
  bf16x8 qf = *(const bf16x8*)(qkv + (pixbase + (size_t)gy * IMG + gx) * MQKV + hd * 96 + g16 * 8);

  // relb -> Pq[0..2047]
  *(uint4*)(Pq + tid * 8) = *(const uint4*)(relb + tid * 8);

  // stage K (rows, b64 pairs) and V (transposed scatter) over padded key space.
  // 224*8 / 256 = 7 exact iterations; pad/OOB keys write zeros (covers all LDS).
  for (int idx = tid; idx < 224 * 8; idx += 256) {
    int key = idx >> 3, part = idx & 7;
    int ky = key >> 4, kx = key & 15;
    int sy = by * BSZ - HALO + ky, sx = bx * BSZ - HALO + kx;
    uint4 val = make_uint4(0,0,0,0);
    if (kx < WIN && (unsigned)sy < (unsigned)IMG && (unsigned)sx < (unsigned)IMG)
      val = *(const uint4*)(qkv + (pixbase + sy * IMG + sx) * MQKV + hd * 96 + 32 + part * 8);
    if (part < 4) {
      unsigned short* kp = Ks + key * KS_STRIDE + part * 8;
      *(unsigned long long*)(kp    ) = (unsigned long long)val.x | ((unsigned long long)val.y << 32);
      *(unsigned long long*)(kp + 4) = (unsigned long long)val.z | ((unsigned long long)val.w << 32);
    } else {
      int dh0 = (part - 4) * 8;
      unsigned int u[4] = {val.x, val.y, val.z, val.w};
      #pragma unroll
      for (int e = 0; e < 4; ++e) {
        Vt[(dh0 + 2*e    ) * VT_STRIDE + key] = (unsigned short)(u[e] & 0xffffu);
        Vt[(dh0 + 2*e + 1) * VT_STRIDE + key] = (unsigned short)(u[e] >> 16);
      }
    }
  }
  __syncthreads();

  // ---- bias via MFMA: C[t][q] = rel[t] . q ----
  {
    const unsigned short* Hb = Pq;
    const unsigned short* Wr = Pq + 1024;
    bf16x8 ah0 = *(const bf16x8*)(Hb + l15 * 32 + g16 * 8);
    bf16x8 ah1 = *(const bf16x8*)(Hb + (16 + l15) * 32 + g16 * 8);
    bf16x8 aw0 = *(const bf16x8*)(Wr + l15 * 32 + g16 * 8);
    bf16x8 aw1 = *(const bf16x8*)(Wr + (16 + l15) * 32 + g16 * 8);
    f32x4 z = (f32x4){0.f,0.f,0.f,0.f};
    f32x4 ch0 = __builtin_amdgcn_mfma_f32_16x16x32_bf16(ah0, qf, z, 0, 0, 0);
    f32x4 ch1 = __builtin_amdgcn_mfma_f32_16x16x32_bf16(ah1, qf, z, 0, 0, 0);
    f32x4 cw0 = __builtin_amdgcn_mfma_f32_16x16x32_bf16(aw0, qf, z, 0, 0, 0);
    f32x4 cw1 = __builtin_amdgcn_mfma_f32_16x16x32_bf16(aw1, qf, z, 0, 0, 0);
    unsigned short* QBq = QB + q * QB_STRIDE;
    st_bf4c(QBq +      (( 0 + g16 * 4 + rot) & 31), ch0);
    st_bf4c(QBq +      ((16 + g16 * 4 + rot) & 31), ch1);
    st_bf4c(QBq + 32 + (( 0 + g16 * 4 + rot) & 31), cw0);
    st_bf4c(QBq + 32 + ((16 + g16 * 4 + rot) & 31), cw1);
  }
  __syncthreads();   // all waves done reading relb region before Pq P-writes

  const unsigned short* QBq = QB + q * QB_STRIDE;
  unsigned short* Prow = Pq + q * PQ_STRIDE;

  const float LOG2E = 1.4426950408889634f;
  const float SL2E  = SCALE * LOG2E;

  // loop-invariant w-bias (x log2e); pad kx>=14 -> -1e30 masks via exp2->0
  float bw2[4];
  #pragma unroll
  for (int i = 0; i < 4; ++i) {
    int kx = g16 * 4 + i;
    bw2[i] = (kx < WIN) ? bf2f(QBq[32 + ((kx - qx + 13 + rot) & 31)]) * LOG2E : -1e30f;
  }
  const int hbase = 13 - qy + rot;                 // h-region read base (rotated)

  float lsum = 0.f;
  f32x4 o0 = (f32x4){0.f,0.f,0.f,0.f}, o1 = (f32x4){0.f,0.f,0.f,0.f};
  const f32x4 z = (f32x4){0.f,0.f,0.f,0.f};

  #pragma unroll
  for (int half = 0; half < 2; ++half) {
    #pragma unroll
    for (int u = 0; u < 7; ++u) {
      const int nt = half * 7 + u;                 // == ky of this tile
      bf16x8 kf = ld2(Ks + (nt * 16 + l15) * KS_STRIDE + g16 * 8);
      f32x4 c = __builtin_amdgcn_mfma_f32_16x16x32_bf16(kf, qf, z, 0, 0, 0);
      float bh2 = bf2f(QBq[(nt + hbase) & 31]) * LOG2E; // per-tile-constant h-bias
      float p0 = exp2f(fmaf(c[0], SL2E, bh2 + bw2[0]));
      float p1 = exp2f(fmaf(c[1], SL2E, bh2 + bw2[1]));
      float p2 = exp2f(fmaf(c[2], SL2E, bh2 + bw2[2]));
      float p3 = exp2f(fmaf(c[3], SL2E, bh2 + bw2[3]));
      lsum += (p0 + p1) + (p2 + p3);
      unsigned int plo, phi;
      asm("v_cvt_pk_bf16_f32 %0, %1, %2" : "=v"(plo) : "v"(p0), "v"(p1));
      asm("v_cvt_pk_bf16_f32 %0, %1, %2" : "=v"(phi) : "v"(p2), "v"(p3));
      union { unsigned int u32[2]; u16x4 v; } pk_;
      pk_.u32[0] = plo; pk_.u32[1] = phi;
      *(u16x4*)(Prow + u * 16 + g16 * 4) = pk_.v;  // ushort-typed store (aliases pf loads)
    }
    asm volatile("" ::: "memory");                 // order P-writes before pf reads
    #pragma unroll
    for (int cc = 0; cc < 4; ++cc) {
      bf16x8 pf = (bf16x8){0,0,0,0,0,0,0,0};
      const bool masked = (cc == 3);               // last 16 keys of half only
      if (!masked || g16 < 2)
        pf = *(const bf16x8*)(Prow + cc * 32 + g16 * 8);
      int vcol = half * 112 + cc * 32 + g16 * 8;
      if (masked && g16 >= 2) vcol = 0;            // pf==0; keep read in-bounds
      bf16x8 v0 = ld2(Vt + l15 * VT_STRIDE + vcol);
      bf16x8 v1 = ld2(Vt + (16 + l15) * VT_STRIDE + vcol);
      o0 = __builtin_amdgcn_mfma_f32_16x16x32_bf16(v0, pf, o0, 0, 0, 0);
      o1 = __builtin_amdgcn_mfma_f32_16x16x32_bf16(v1, pf, o1, 0, 0, 0);
    }
  }

  lsum += __shfl_xor(lsum, 16);
  lsum += __shfl_xor(lsum, 32);
  float inv = 1.f / lsum;

  float* ob = out + (((size_t)(b0 + bb) * 256 + hd * DH) * HWPIX) + (size_t)gy * IMG + gx;
  #pragma unroll
  for (int i = 0; i < 4; ++i) {
    int dh0 = g16 * 4 + i;
    ob[(size_t)dh0 * HWPIX]        = o0[i] * inv;
    ob[(size_t)(dh0 + 16) * HWPIX] = o1[i] * inv;
  }
}

// ---------------------------------------------------------------------------
extern "C" void kernel_launch(void* const* d_in, const int* in_sizes, int n_in,
                              void* d_out, int out_size, void* d_ws, size_t ws_size,
                              hipStream_t stream)
{
  (void)in_sizes; (void)n_in; (void)out_size;
  const float* x    = (const float*)d_in[0];
  const float* wq   = (const float*)d_in[1];
  const float* wkv  = (const float*)d_in[2];
  const float* hrel = (const float*)d_in[3];
  const float* wrel = (const float*)d_in[4];
  float* out = (float*)d_out;

  const size_t wb_bytes   = (size_t)MQKV * CIN * 2;      // 393216
  const size_t relb_bytes = 4096;
  const size_t qkv_per_b  = (size_t)HWPIX * MQKV * 2;    // 25.2 MB
  const int chunk = (ws_size >= wb_bytes + relb_bytes + 4 * qkv_per_b) ? 4 : 1;

  unsigned short* Wb   = (unsigned short*)d_ws;
  unsigned short* relb = (unsigned short*)((char*)d_ws + wb_bytes);
  unsigned short* qkv  = (unsigned short*)((char*)d_ws + wb_bytes + relb_bytes);

  convw_kernel<<<192, 256, 0, stream>>>(wq, wkv, Wb);
  convrel_kernel<<<8, 256, 0, stream>>>(hrel, wrel, relb);

  for (int b0 = 0; b0 < 4; b0 += chunk) {
    projx_kernel<<<dim3(256, chunk), 256, 0, stream>>>(x + (size_t)b0 * CIN * HWPIX, Wb, qkv);
    attn_kernel<<<dim3(256, HEADS, chunk), 256, 0, stream>>>(qkv, relb, out, b0);
  }
}

// Round 15
// 242.113 us; speedup vs baseline: 1.3827x; 1.0166x over previous
//
#include <hip/hip_runtime.h>
#include <hip/hip_bf16.h>
#include <stdint.h>

#define HEADS 8
#define DH    32
#define BSZ   8
#define HALO  3
#define WIN   14
#define NKEY  196
#define CIN   256
#define IMG   128
#define HWPIX 16384
#define MQKV  768         // 8 heads x (q32 + k32 + v32), head-blocked
#define SCALE 0.17677669529663689f  // 32^-0.5

#define KS_STRIDE 36      // shorts, 72 B rows (8B aligned, l15*18dw: 16 distinct banks)
#define VT_STRIDE 228     // shorts (114 dw; holds 224 padded keys)
#define QB_STRIDE 64      // shorts; rows bank-aliased, fixed by per-row rotation rot=(q&7)*4

#define BST_STRIDE 264    // shorts per Bst pixel row (132 dw == 4 mod 32: 2-way reads)
#define AS_STRIDE  68     // shorts per As row: 34 dw odd-pair -> af reads ~2-way (64 was 16-way!)

typedef short bf16x8 __attribute__((ext_vector_type(8)));
typedef short bf16x4 __attribute__((ext_vector_type(4)));
typedef float f32x4  __attribute__((ext_vector_type(4)));
typedef unsigned short u16x4 __attribute__((ext_vector_type(4)));
typedef unsigned short u16x8 __attribute__((ext_vector_type(8)));

#define AS1 __attribute__((address_space(1)))
#define AS3 __attribute__((address_space(3)))

__device__ __forceinline__ float bf2f(unsigned short s){ return __uint_as_float(((unsigned int)s) << 16); }
__device__ __forceinline__ unsigned short f2bf(float f){        // RNE (cold paths only)
  unsigned int u = __float_as_uint(f);
  u += 0x7fffu + ((u >> 16) & 1u);
  return (unsigned short)(u >> 16);
}

// ---- conversion idiom (r3/r6/r13 lesson) ----
// Inline-asm v_cvt_pk reading MFMA (AGPR) outputs miscompiles silently (3x NaN).
// COMPILER casts (__float22bfloat162_rn, RNE) emit cvt_pk AND handle the
// AGPR->VGPR transfer correctly. asm cvt_pk only on plain VALU values (P-path).
__device__ __forceinline__ ushort2 pk2c(float a, float b) {
  __hip_bfloat162 h = __float22bfloat162_rn(make_float2(a, b));
  union { __hip_bfloat162 h2; ushort2 v; } r; r.h2 = h; return r.v;
}
__device__ __forceinline__ void st_bf4c(unsigned short* p, f32x4 c) {
  ushort2 lo = pk2c(c[0], c[1]), hi = pk2c(c[2], c[3]);
  ushort4 o; o.x = lo.x; o.y = lo.y; o.z = hi.x; o.w = hi.y;
  *(ushort4*)p = o;
}

// 8-short fragment from two 8B-aligned LDS halves
__device__ __forceinline__ bf16x8 ld2(const unsigned short* p) {
  bf16x4 a = *(const bf16x4*)p;
  bf16x4 b = *(const bf16x4*)(p + 4);
  bf16x8 r;
  r[0]=a[0]; r[1]=a[1]; r[2]=a[2]; r[3]=a[3];
  r[4]=b[0]; r[5]=b[1]; r[6]=b[2]; r[7]=b[3];
  return r;
}

// ---------------------------------------------------------------------------
// W fp32 -> bf16, head-blocked rows: m = h*96 + d; d<32 -> wq[h*32+d],
// d in [32,96) -> wkv[h*64 + d-32].
// ---------------------------------------------------------------------------
__global__ void convw_kernel(const float* __restrict__ wq,
                             const float* __restrict__ wkv,
                             unsigned short* __restrict__ Wb)
{
  int idx = blockIdx.x * 256 + threadIdx.x;      // 768 rows x 64 float4
  int m = idx >> 6, c4 = idx & 63;
  int h = m / 96, d = m - h * 96;
  const float* src = (d < 32) ? wq  + (size_t)(h * 32 + d) * CIN
                              : wkv + (size_t)(h * 64 + d - 32) * CIN;
  float4 v = *(const float4*)(src + c4 * 4);
  ushort4 o;
  o.x = f2bf(v.x); o.y = f2bf(v.y); o.z = f2bf(v.z); o.w = f2bf(v.w);
  *(ushort4*)(Wb + (size_t)m * CIN + c4 * 4) = o;
}

// ---------------------------------------------------------------------------
// rel tables -> bf16 [64][32]: rows 0..26 hrel, 27..31 zero, 32..58 wrel, 59..63 zero
// ---------------------------------------------------------------------------
__global__ void convrel_kernel(const float* __restrict__ hrel,
                               const float* __restrict__ wrel,
                               unsigned short* __restrict__ relb)
{
  int idx = blockIdx.x * 256 + threadIdx.x;      // 2048
  int r = idx >> 5, c = idx & 31;
  float v = 0.f;
  if (r < 27) v = hrel[r * 32 + c];
  else if (r >= 32 && r < 59) v = wrel[(r - 32) * 32 + c];
  relb[idx] = f2bf(v);
}

// ---------------------------------------------------------------------------
// Phase 1 (fused): projection GEMM reading x f32 directly.  (r14 verbatim —
// reg-staged A, padded As, issue-early loads, compiler-cast conversions.)
// LDS: Bst 33792 + As 17408 = 51200 B = 13 x 4KiB pages -> 3 blocks/CU.
// ---------------------------------------------------------------------------
__global__ __launch_bounds__(256, 3)
void projx_kernel(const float* __restrict__ x,            // chunk base [bl][256][16384] f32
                  const unsigned short* __restrict__ Wb,  // [768][256]
                  unsigned short* __restrict__ qkv)       // [chunk*16384][768]
{
  __shared__ unsigned short Bst[64 * BST_STRIDE];  // 33792 B [pix][256cin] (padded rows)
  __shared__ unsigned short As[128 * AS_STRIDE];   // 17408 B A tile (padded); E reuses front

  const int tid = threadIdx.x;
  const int w = tid >> 6, lane = tid & 63;
  const int g16 = lane >> 4, l15 = lane & 15;
  const int p0 = blockIdx.x * 64;
  const int bl = blockIdx.y;
  const int wm = w >> 1, wn = w & 1;
  const float* xin = x + (size_t)bl * CIN * HWPIX;

  const int arow = lane >> 3;            // 0..7 row within this thread's ci-block
  const int acol = (lane & 7) * 8;       // 0..56 col (shorts)

  // issue A loads for (mt=0,kk=0) FIRST — in flight during the Bst staging
  bf16x8 areg[4];
  #pragma unroll
  for (int c = 0; c < 4; ++c) {
    int ci = w * 4 + c;
    areg[c] = *(const bf16x8*)(Wb + (size_t)(ci * 8 + arow) * CIN + acol);
  }

  // ---- stage B: x[cin][pix] f32 -> Bst[pix][cin] bf16 (convx T-pattern) ----
  for (int idx = tid; idx < 2048; idx += 256) {
    int cp = idx >> 4, f = idx & 15;
    const float* r0 = xin + (size_t)(2 * cp) * HWPIX + p0 + f * 4;
    float4 a = *(const float4*)r0;
    float4 b = *(const float4*)(r0 + HWPIX);
    unsigned short* bp = Bst + (f * 4) * BST_STRIDE + cp * 2;
    *(ushort2*)(bp                 ) = pk2c(a.x, b.x);
    *(ushort2*)(bp + BST_STRIDE    ) = pk2c(a.y, b.y);
    *(ushort2*)(bp + BST_STRIDE * 2) = pk2c(a.z, b.z);
    *(ushort2*)(bp + BST_STRIDE * 3) = pk2c(a.w, b.w);
  }
  __syncthreads();

  // ---- m-tile loop: all 6 output tiles from the resident B ----
  for (int mt = 0; mt < 6; ++mt) {
    f32x4 acc[4][2];
    #pragma unroll
    for (int i = 0; i < 4; ++i)
      #pragma unroll
      for (int j = 0; j < 2; ++j) acc[i][j] = (f32x4){0.f,0.f,0.f,0.f};

    #pragma unroll
    for (int kk = 0; kk < 4; ++kk) {
      // write staged A regs -> As (short-family b128 stores; padded stride)
      #pragma unroll
      for (int c = 0; c < 4; ++c) {
        int ci = w * 4 + c;
        *(bf16x8*)(As + (ci * 8 + arow) * AS_STRIDE + acol) = areg[c];
      }
      __syncthreads();

      // issue NEXT tile's A loads now — they fly during the MFMAs below
      {
        int nit = mt * 4 + kk + 1;
        if (nit < 24) {
          int nm0 = (nit >> 2) * 128, nk0 = (nit & 3) * 64;
          #pragma unroll
          for (int c = 0; c < 4; ++c) {
            int ci = w * 4 + c;
            areg[c] = *(const bf16x8*)(Wb + (size_t)(nm0 + ci * 8 + arow) * CIN + nk0 + acol);
          }
        }
      }

      const int k0 = kk * 64;
      #pragma unroll
      for (int kh = 0; kh < 2; ++kh) {
        bf16x8 af[4], bfr[2];
        #pragma unroll
        for (int t = 0; t < 4; ++t)
          af[t] = *(const bf16x8*)(As + (wm*64 + t*16 + l15) * AS_STRIDE + kh*32 + g16*8);
        #pragma unroll
        for (int t = 0; t < 2; ++t)
          bfr[t] = *(const bf16x8*)(Bst + (wn*32 + t*16 + l15)*BST_STRIDE + k0 + kh*32 + g16*8);
        #pragma unroll
        for (int tm = 0; tm < 4; ++tm)
          #pragma unroll
          for (int tn = 0; tn < 2; ++tn)
            acc[tm][tn] = __builtin_amdgcn_mfma_f32_16x16x32_bf16(
                            af[tm], bfr[tn], acc[tm][tn], 0, 0, 0);
      }
      __syncthreads();                    // As reads done before next kk's write
    }

    // ---- epilogue for this mt: acc -> E (swizzled, front of As) -> coalesced ----
    const int m0 = mt * 128;
    #pragma unroll
    for (int tm = 0; tm < 4; ++tm) {
      int ch = wm*64 + tm*16 + g16*4;
      #pragma unroll
      for (int tn = 0; tn < 2; ++tn) {
        int pix = wn*32 + tn*16 + l15;
        unsigned int boff = (unsigned)(pix*256 + ((ch*2) ^ ((l15 & 7) << 4)));
        st_bf4c((unsigned short*)((char*)As + boff), acc[tm][tn]);
      }
    }
    __syncthreads();
    {
      unsigned short* qrow = qkv + ((size_t)bl * HWPIX + p0) * MQKV + m0;
      #pragma unroll
      for (int r = 0; r < 4; ++r) {
        int pl = w*16 + r*4 + g16;               // 0..63, bijective over threads x r
        unsigned int boff = (unsigned)(pl*256 + ((l15*16) ^ ((pl & 7) << 4)));
        u16x8 vv = *(const u16x8*)((const char*)As + boff);
        *(u16x8*)(qrow + (size_t)pl * MQKV + l15*8) = vv;
      }
    }
    __syncthreads();                             // E reads done before next mt's As writes
  }
}

// ---------------------------------------------------------------------------
// Phase 2: fused halo attention, MFMA bf16.
// r15: Pq ELIMINATED — P is exchanged in-register via __shfl among the 4
// lanes sharing a q-row (lanes l15, +16, +32, +48 of one wave; consumer
// (g16,cc) needs tile u_src = 2cc+(g16>>1) from producer groups A=2(g16&1),
// B=A+1 — index map verified against the old LDS address map). relb transient
// moves to QB (4KB of 8KB); barrier between relb reads and QB bias writes.
// LDS: Ks 16128 + Vt 14592 + QB 8192 = 38912 B = 10 x 4KiB pages ->
// 4 blocks/CU (was 3) — the occupancy lever (attn is latency-bound:
// MFMA 7% / VALU 52% / HBM 19%, nothing saturated).
// ---------------------------------------------------------------------------
__global__ __launch_bounds__(256, 4)
void attn_kernel(const unsigned short* __restrict__ qkv,  // chunk base
                 const unsigned short* __restrict__ relb, // [64][32] bf16
                 float* __restrict__ out,                 // [4][256][128][128]
                 int b0)
{
  __shared__ unsigned short Ks[224 * KS_STRIDE];   // 16128 B [ky*16+kx][dh]
  __shared__ unsigned short Vt[32 * VT_STRIDE];    // 14592 B [dh][ky*16+kx]
  __shared__ unsigned short QB[64 * QB_STRIDE];    //  8192 B bias rows (first 4KB = relb transient)

  const int tid = threadIdx.x;
  const int by = blockIdx.x >> 4, bx = blockIdx.x & 15;
  const int hd = blockIdx.y, bb = blockIdx.z;
  const size_t pixbase = (size_t)bb * HWPIX;

  const int w = tid >> 6, lane = tid & 63;
  const int g16 = lane >> 4, l15 = lane & 15;
  const int q = w * 16 + l15;
  const int qy = q >> 3, qx = q & 7;
  const int gy = by * BSZ + qy, gx = bx * BSZ + qx;
  const int rot = qx * 4;                          // per-row bank rotation

  // own q fragment (B-operand for both bias and QK MFMAs)
  bf16x8 qf = *(const bf16x8*)(qkv + (pixbase + (size_t)gy * IMG + gx) * MQKV + hd * 96 + g16 * 8);

  // relb -> QB[0..2047] (transient; consumed by bias loads below)
  *(uint4*)(QB + tid * 8) = *(const uint4*)(relb + tid * 8);

  // stage K (rows, b64 pairs) and V (transposed scatter) over padded key space.
  // 224*8 / 256 = 7 exact iterations; pad/OOB keys write zeros (covers all LDS).
  for (int idx = tid; idx < 224 * 8; idx += 256) {
    int key = idx >> 3, part = idx & 7;
    int ky = key >> 4, kx = key & 15;
    int sy = by * BSZ - HALO + ky, sx = bx * BSZ - HALO + kx;
    uint4 val = make_uint4(0,0,0,0);
    if (kx < WIN && (unsigned)sy < (unsigned)IMG && (unsigned)sx < (unsigned)IMG)
      val = *(const uint4*)(qkv + (pixbase + sy * IMG + sx) * MQKV + hd * 96 + 32 + part * 8);
    if (part < 4) {
      unsigned short* kp = Ks + key * KS_STRIDE + part * 8;
      *(unsigned long long*)(kp    ) = (unsigned long long)val.x | ((unsigned long long)val.y << 32);
      *(unsigned long long*)(kp + 4) = (unsigned long long)val.z | ((unsigned long long)val.w << 32);
    } else {
      int dh0 = (part - 4) * 8;
      unsigned int u[4] = {val.x, val.y, val.z, val.w};
      #pragma unroll
      for (int e = 0; e < 4; ++e) {
        Vt[(dh0 + 2*e    ) * VT_STRIDE + key] = (unsigned short)(u[e] & 0xffffu);
        Vt[(dh0 + 2*e + 1) * VT_STRIDE + key] = (unsigned short)(u[e] >> 16);
      }
    }
  }
  __syncthreads();   // staging + relb transient complete

  // ---- bias via MFMA: C[t][q] = rel[t] . q  (rel from QB transient) ----
  {
    const unsigned short* Hb = QB;
    const unsigned short* Wr = QB + 1024;
    bf16x8 ah0 = *(const bf16x8*)(Hb + l15 * 32 + g16 * 8);
    bf16x8 ah1 = *(const bf16x8*)(Hb + (16 + l15) * 32 + g16 * 8);
    bf16x8 aw0 = *(const bf16x8*)(Wr + l15 * 32 + g16 * 8);
    bf16x8 aw1 = *(const bf16x8*)(Wr + (16 + l15) * 32 + g16 * 8);
    __syncthreads();  // ALL lanes' relb reads done before bias writes overwrite QB
    f32x4 z = (f32x4){0.f,0.f,0.f,0.f};
    f32x4 ch0 = __builtin_amdgcn_mfma_f32_16x16x32_bf16(ah0, qf, z, 0, 0, 0);
    f32x4 ch1 = __builtin_amdgcn_mfma_f32_16x16x32_bf16(ah1, qf, z, 0, 0, 0);
    f32x4 cw0 = __builtin_amdgcn_mfma_f32_16x16x32_bf16(aw0, qf, z, 0, 0, 0);
    f32x4 cw1 = __builtin_amdgcn_mfma_f32_16x16x32_bf16(aw1, qf, z, 0, 0, 0);
    unsigned short* QBq = QB + q * QB_STRIDE;
    st_bf4c(QBq +      (( 0 + g16 * 4 + rot) & 31), ch0);
    st_bf4c(QBq +      ((16 + g16 * 4 + rot) & 31), ch1);
    st_bf4c(QBq + 32 + (( 0 + g16 * 4 + rot) & 31), cw0);
    st_bf4c(QBq + 32 + ((16 + g16 * 4 + rot) & 31), cw1);
  }
  __syncthreads();   // bias rows complete (own-wave reads follow; cheap insurance)

  const unsigned short* QBq = QB + q * QB_STRIDE;

  const float LOG2E = 1.4426950408889634f;
  const float SL2E  = SCALE * LOG2E;

  // loop-invariant w-bias (x log2e); pad kx>=14 -> -1e30 masks via exp2->0
  float bw2[4];
  #pragma unroll
  for (int i = 0; i < 4; ++i) {
    int kx = g16 * 4 + i;
    bw2[i] = (kx < WIN) ? bf2f(QBq[32 + ((kx - qx + 13 + rot) & 31)]) * LOG2E : -1e30f;
  }
  const int hbase = 13 - qy + rot;                 // h-region read base (rotated)

  // P-exchange lane map: the 4 lanes sharing q are l15 + 16*{0,1,2,3}
  const int srcA = l15 + ((g16 & 1) ? 32 : 0);     // group 2(g16&1)
  const int srcB = srcA + 16;                      // group 2(g16&1)+1
  const bool hiTile = (g16 >> 1) != 0;

  float lsum = 0.f;
  f32x4 o0 = (f32x4){0.f,0.f,0.f,0.f}, o1 = (f32x4){0.f,0.f,0.f,0.f};
  const f32x4 z = (f32x4){0.f,0.f,0.f,0.f};

  #pragma unroll
  for (int half = 0; half < 2; ++half) {
    unsigned int Plo[7], Phi[7];                   // this half's P tiles, in-register
    #pragma unroll
    for (int u = 0; u < 7; ++u) {
      const int nt = half * 7 + u;                 // == ky of this tile
      bf16x8 kf = ld2(Ks + (nt * 16 + l15) * KS_STRIDE + g16 * 8);
      f32x4 c = __builtin_amdgcn_mfma_f32_16x16x32_bf16(kf, qf, z, 0, 0, 0);
      float bh2 = bf2f(QBq[(nt + hbase) & 31]) * LOG2E; // per-tile-constant h-bias
      float p0 = exp2f(fmaf(c[0], SL2E, bh2 + bw2[0]));
      float p1 = exp2f(fmaf(c[1], SL2E, bh2 + bw2[1]));
      float p2 = exp2f(fmaf(c[2], SL2E, bh2 + bw2[2]));
      float p3 = exp2f(fmaf(c[3], SL2E, bh2 + bw2[3]));
      lsum += (p0 + p1) + (p2 + p3);
      unsigned int plo, phi;                       // asm cvt_pk on VALU values (proven)
      asm("v_cvt_pk_bf16_f32 %0, %1, %2" : "=v"(plo) : "v"(p0), "v"(p1));
      asm("v_cvt_pk_bf16_f32 %0, %1, %2" : "=v"(phi) : "v"(p2), "v"(p3));
      Plo[u] = plo; Phi[u] = phi;
    }
    #pragma unroll
    for (int cc = 0; cc < 4; ++cc) {
      const int ua = 2 * cc;
      const int ub = (cc < 3) ? (2 * cc + 1) : 6;  // cc=3: dummy (masked consumers)
      unsigned int a0 = __shfl(Plo[ua], srcA, 64), a1 = __shfl(Phi[ua], srcA, 64);
      unsigned int b0 = __shfl(Plo[ub], srcA, 64), b1 = __shfl(Phi[ub], srcA, 64);
      unsigned int c0 = __shfl(Plo[ua], srcB, 64), c1 = __shfl(Phi[ua], srcB, 64);
      unsigned int d0 = __shfl(Plo[ub], srcB, 64), d1 = __shfl(Phi[ub], srcB, 64);
      union { unsigned int u32[4]; bf16x8 v; } pfu;
      pfu.u32[0] = hiTile ? b0 : a0;
      pfu.u32[1] = hiTile ? b1 : a1;
      pfu.u32[2] = hiTile ? d0 : c0;
      pfu.u32[3] = hiTile ? d1 : c1;
      bf16x8 pf = pfu.v;
      const bool masked = (cc == 3);               // last 16 keys of half only
      if (masked && g16 >= 2) pf = (bf16x8){0,0,0,0,0,0,0,0};
      int vcol = half * 112 + cc * 32 + g16 * 8;
      if (masked && g16 >= 2) vcol = 0;            // pf==0; keep read in-bounds
      bf16x8 v0 = ld2(Vt + l15 * VT_STRIDE + vcol);
      bf16x8 v1 = ld2(Vt + (16 + l15) * VT_STRIDE + vcol);
      o0 = __builtin_amdgcn_mfma_f32_16x16x32_bf16(v0, pf, o0, 0, 0, 0);
      o1 = __builtin_amdgcn_mfma_f32_16x16x32_bf16(v1, pf, o1, 0, 0, 0);
    }
  }

  lsum += __shfl_xor(lsum, 16);
  lsum += __shfl_xor(lsum, 32);
  float inv = 1.f / lsum;

  float* ob = out + (((size_t)(b0 + bb) * 256 + hd * DH) * HWPIX) + (size_t)gy * IMG + gx;
  #pragma unroll
  for (int i = 0; i < 4; ++i) {
    int dh0 = g16 * 4 + i;
    ob[(size_t)dh0 * HWPIX]        = o0[i] * inv;
    ob[(size_t)(dh0 + 16) * HWPIX] = o1[i] * inv;
  }
}

// ---------------------------------------------------------------------------
extern "C" void kernel_launch(void* const* d_in, const int* in_sizes, int n_in,
                              void* d_out, int out_size, void* d_ws, size_t ws_size,
                              hipStream_t stream)
{
  (void)in_sizes; (void)n_in; (void)out_size;
  const float* x    = (const float*)d_in[0];
  const float* wq   = (const float*)d_in[1];
  const float* wkv  = (const float*)d_in[2];
  const float* hrel = (const float*)d_in[3];
  const float* wrel = (const float*)d_in[4];
  float* out = (float*)d_out;

  const size_t wb_bytes   = (size_t)MQKV * CIN * 2;      // 393216
  const size_t relb_bytes = 4096;
  const size_t qkv_per_b  = (size_t)HWPIX * MQKV * 2;    // 25.2 MB
  const int chunk = (ws_size >= wb_bytes + relb_bytes + 4 * qkv_per_b) ? 4 : 1;

  unsigned short* Wb   = (unsigned short*)d_ws;
  unsigned short* relb = (unsigned short*)((char*)d_ws + wb_bytes);
  unsigned short* qkv  = (unsigned short*)((char*)d_ws + wb_bytes + relb_bytes);

  convw_kernel<<<192, 256, 0, stream>>>(wq, wkv, Wb);
  convrel_kernel<<<8, 256, 0, stream>>>(hrel, wrel, relb);

  for (int b0 = 0; b0 < 4; b0 += chunk) {
    projx_kernel<<<dim3(256, chunk), 256, 0, stream>>>(x + (size_t)b0 * CIN * HWPIX, Wb, qkv);
    attn_kernel<<<dim3(256, HEADS, chunk), 256, 0, stream>>>(qkv, relb, out, b0);
  }
}

// Round 16
// 238.538 us; speedup vs baseline: 1.4034x; 1.0150x over previous
//
#include <hip/hip_runtime.h>
#include <hip/hip_bf16.h>
#include <stdint.h>

#define HEADS 8
#define DH    32
#define BSZ   8
#define HALO  3
#define WIN   14
#define NKEY  196
#define CIN   256
#define IMG   128
#define HWPIX 16384
#define MQKV  768         // 8 heads x (q32 + k32 + v32), head-blocked
#define SCALE 0.17677669529663689f  // 32^-0.5

#define KS_STRIDE 36      // shorts, 72 B rows (8B aligned, l15*18dw: 16 distinct banks)
#define VT_STRIDE 228     // shorts (114 dw; holds 224 padded keys)
#define QB_STRIDE 64      // shorts; rows bank-aliased, fixed by per-row rotation rot=(q&7)*4

#define BST_STRIDE 264    // shorts per Bst pixel row (132 dw == 4 mod 32: 2-way reads)
#define AS_STRIDE  68     // shorts per As row: 34 dw odd-pair -> af reads ~2-way (64 was 16-way!)

typedef short bf16x8 __attribute__((ext_vector_type(8)));
typedef short bf16x4 __attribute__((ext_vector_type(4)));
typedef float f32x4  __attribute__((ext_vector_type(4)));
typedef unsigned short u16x4 __attribute__((ext_vector_type(4)));
typedef unsigned short u16x8 __attribute__((ext_vector_type(8)));

#define AS1 __attribute__((address_space(1)))
#define AS3 __attribute__((address_space(3)))

__device__ __forceinline__ float bf2f(unsigned short s){ return __uint_as_float(((unsigned int)s) << 16); }
__device__ __forceinline__ unsigned short f2bf(float f){        // RNE (cold paths only)
  unsigned int u = __float_as_uint(f);
  u += 0x7fffu + ((u >> 16) & 1u);
  return (unsigned short)(u >> 16);
}

// ---- conversion idiom (r3/r6/r13 lesson) ----
// Inline-asm v_cvt_pk reading MFMA (AGPR) outputs miscompiles silently (3x NaN).
// COMPILER casts (__float22bfloat162_rn, RNE) emit cvt_pk AND handle the
// AGPR->VGPR transfer correctly. asm cvt_pk only on plain VALU values (P-path).
__device__ __forceinline__ ushort2 pk2c(float a, float b) {
  __hip_bfloat162 h = __float22bfloat162_rn(make_float2(a, b));
  union { __hip_bfloat162 h2; ushort2 v; } r; r.h2 = h; return r.v;
}
__device__ __forceinline__ void st_bf4c(unsigned short* p, f32x4 c) {
  ushort2 lo = pk2c(c[0], c[1]), hi = pk2c(c[2], c[3]);
  ushort4 o; o.x = lo.x; o.y = lo.y; o.z = hi.x; o.w = hi.y;
  *(ushort4*)p = o;
}

// 8-short fragment from two 8B-aligned LDS halves
__device__ __forceinline__ bf16x8 ld2(const unsigned short* p) {
  bf16x4 a = *(const bf16x4*)p;
  bf16x4 b = *(const bf16x4*)(p + 4);
  bf16x8 r;
  r[0]=a[0]; r[1]=a[1]; r[2]=a[2]; r[3]=a[3];
  r[4]=b[0]; r[5]=b[1]; r[6]=b[2]; r[7]=b[3];
  return r;
}

// ---------------------------------------------------------------------------
// W fp32 -> bf16, head-blocked rows: m = h*96 + d; d<32 -> wq[h*32+d],
// d in [32,96) -> wkv[h*64 + d-32].
// ---------------------------------------------------------------------------
__global__ void convw_kernel(const float* __restrict__ wq,
                             const float* __restrict__ wkv,
                             unsigned short* __restrict__ Wb)
{
  int idx = blockIdx.x * 256 + threadIdx.x;      // 768 rows x 64 float4
  int m = idx >> 6, c4 = idx & 63;
  int h = m / 96, d = m - h * 96;
  const float* src = (d < 32) ? wq  + (size_t)(h * 32 + d) * CIN
                              : wkv + (size_t)(h * 64 + d - 32) * CIN;
  float4 v = *(const float4*)(src + c4 * 4);
  ushort4 o;
  o.x = f2bf(v.x); o.y = f2bf(v.y); o.z = f2bf(v.z); o.w = f2bf(v.w);
  *(ushort4*)(Wb + (size_t)m * CIN + c4 * 4) = o;
}

// ---------------------------------------------------------------------------
// rel tables -> bf16 [64][32]: rows 0..26 hrel, 27..31 zero, 32..58 wrel, 59..63 zero
// ---------------------------------------------------------------------------
__global__ void convrel_kernel(const float* __restrict__ hrel,
                               const float* __restrict__ wrel,
                               unsigned short* __restrict__ relb)
{
  int idx = blockIdx.x * 256 + threadIdx.x;      // 2048
  int r = idx >> 5, c = idx & 31;
  float v = 0.f;
  if (r < 27) v = hrel[r * 32 + c];
  else if (r >= 32 && r < 59) v = wrel[(r - 32) * 32 + c];
  relb[idx] = f2bf(v);
}

// ---------------------------------------------------------------------------
// Phase 1 (fused): projection GEMM reading x f32 directly.  (r14 verbatim —
// reg-staged A, padded As, issue-early loads, compiler-cast conversions.)
// At its traffic floor (~73 µs: 256MB x read + 201MB qkv write).
// LDS: Bst 33792 + As 17408 = 51200 B = 13 x 4KiB pages -> 3 blocks/CU.
// ---------------------------------------------------------------------------
__global__ __launch_bounds__(256, 3)
void projx_kernel(const float* __restrict__ x,            // chunk base [bl][256][16384] f32
                  const unsigned short* __restrict__ Wb,  // [768][256]
                  unsigned short* __restrict__ qkv)       // [chunk*16384][768]
{
  __shared__ unsigned short Bst[64 * BST_STRIDE];  // 33792 B [pix][256cin] (padded rows)
  __shared__ unsigned short As[128 * AS_STRIDE];   // 17408 B A tile (padded); E reuses front

  const int tid = threadIdx.x;
  const int w = tid >> 6, lane = tid & 63;
  const int g16 = lane >> 4, l15 = lane & 15;
  const int p0 = blockIdx.x * 64;
  const int bl = blockIdx.y;
  const int wm = w >> 1, wn = w & 1;
  const float* xin = x + (size_t)bl * CIN * HWPIX;

  const int arow = lane >> 3;            // 0..7 row within this thread's ci-block
  const int acol = (lane & 7) * 8;       // 0..56 col (shorts)

  // issue A loads for (mt=0,kk=0) FIRST — in flight during the Bst staging
  bf16x8 areg[4];
  #pragma unroll
  for (int c = 0; c < 4; ++c) {
    int ci = w * 4 + c;
    areg[c] = *(const bf16x8*)(Wb + (size_t)(ci * 8 + arow) * CIN + acol);
  }

  // ---- stage B: x[cin][pix] f32 -> Bst[pix][cin] bf16 (convx T-pattern) ----
  for (int idx = tid; idx < 2048; idx += 256) {
    int cp = idx >> 4, f = idx & 15;
    const float* r0 = xin + (size_t)(2 * cp) * HWPIX + p0 + f * 4;
    float4 a = *(const float4*)r0;
    float4 b = *(const float4*)(r0 + HWPIX);
    unsigned short* bp = Bst + (f * 4) * BST_STRIDE + cp * 2;
    *(ushort2*)(bp                 ) = pk2c(a.x, b.x);
    *(ushort2*)(bp + BST_STRIDE    ) = pk2c(a.y, b.y);
    *(ushort2*)(bp + BST_STRIDE * 2) = pk2c(a.z, b.z);
    *(ushort2*)(bp + BST_STRIDE * 3) = pk2c(a.w, b.w);
  }
  __syncthreads();

  // ---- m-tile loop: all 6 output tiles from the resident B ----
  for (int mt = 0; mt < 6; ++mt) {
    f32x4 acc[4][2];
    #pragma unroll
    for (int i = 0; i < 4; ++i)
      #pragma unroll
      for (int j = 0; j < 2; ++j) acc[i][j] = (f32x4){0.f,0.f,0.f,0.f};

    #pragma unroll
    for (int kk = 0; kk < 4; ++kk) {
      // write staged A regs -> As (short-family b128 stores; padded stride)
      #pragma unroll
      for (int c = 0; c < 4; ++c) {
        int ci = w * 4 + c;
        *(bf16x8*)(As + (ci * 8 + arow) * AS_STRIDE + acol) = areg[c];
      }
      __syncthreads();

      // issue NEXT tile's A loads now — they fly during the MFMAs below
      {
        int nit = mt * 4 + kk + 1;
        if (nit < 24) {
          int nm0 = (nit >> 2) * 128, nk0 = (nit & 3) * 64;
          #pragma unroll
          for (int c = 0; c < 4; ++c) {
            int ci = w * 4 + c;
            areg[c] = *(const bf16x8*)(Wb + (size_t)(nm0 + ci * 8 + arow) * CIN + nk0 + acol);
          }
        }
      }

      const int k0 = kk * 64;
      #pragma unroll
      for (int kh = 0; kh < 2; ++kh) {
        bf16x8 af[4], bfr[2];
        #pragma unroll
        for (int t = 0; t < 4; ++t)
          af[t] = *(const bf16x8*)(As + (wm*64 + t*16 + l15) * AS_STRIDE + kh*32 + g16*8);
        #pragma unroll
        for (int t = 0; t < 2; ++t)
          bfr[t] = *(const bf16x8*)(Bst + (wn*32 + t*16 + l15)*BST_STRIDE + k0 + kh*32 + g16*8);
        #pragma unroll
        for (int tm = 0; tm < 4; ++tm)
          #pragma unroll
          for (int tn = 0; tn < 2; ++tn)
            acc[tm][tn] = __builtin_amdgcn_mfma_f32_16x16x32_bf16(
                            af[tm], bfr[tn], acc[tm][tn], 0, 0, 0);
      }
      __syncthreads();                    // As reads done before next kk's write
    }

    // ---- epilogue for this mt: acc -> E (swizzled, front of As) -> coalesced ----
    const int m0 = mt * 128;
    #pragma unroll
    for (int tm = 0; tm < 4; ++tm) {
      int ch = wm*64 + tm*16 + g16*4;
      #pragma unroll
      for (int tn = 0; tn < 2; ++tn) {
        int pix = wn*32 + tn*16 + l15;
        unsigned int boff = (unsigned)(pix*256 + ((ch*2) ^ ((l15 & 7) << 4)));
        st_bf4c((unsigned short*)((char*)As + boff), acc[tm][tn]);
      }
    }
    __syncthreads();
    {
      unsigned short* qrow = qkv + ((size_t)bl * HWPIX + p0) * MQKV + m0;
      #pragma unroll
      for (int r = 0; r < 4; ++r) {
        int pl = w*16 + r*4 + g16;               // 0..63, bijective over threads x r
        unsigned int boff = (unsigned)(pl*256 + ((l15*16) ^ ((pl & 7) << 4)));
        u16x8 vv = *(const u16x8*)((const char*)As + boff);
        *(u16x8*)(qrow + (size_t)pl * MQKV + l15*8) = vv;
      }
    }
    __syncthreads();                             // E reads done before next mt's As writes
  }
}

// ---------------------------------------------------------------------------
// Phase 2: fused halo attention, MFMA bf16.  (r15 body verbatim.)
// r16: XCD-chunked tile swizzle (T1) — grid.x=256=8x32 exactly; remap so
// XCD i owns tiles i*32..i*32+31 (two contiguous tile-rows). Halo-sharing
// neighbor tiles then hit the SAME per-XCD L2 instead of re-fetching from
// L3/HBM (FETCH was 89MB vs ~59MB logical). Bijective: (bid&7)*32 + (bid>>3).
// LDS: Ks 16128 + Vt 14592 + QB 8192 = 38912 B = 10 pages -> 4 blocks/CU.
// ---------------------------------------------------------------------------
__global__ __launch_bounds__(256, 4)
void attn_kernel(const unsigned short* __restrict__ qkv,  // chunk base
                 const unsigned short* __restrict__ relb, // [64][32] bf16
                 float* __restrict__ out,                 // [4][256][128][128]
                 int b0)
{
  __shared__ unsigned short Ks[224 * KS_STRIDE];   // 16128 B [ky*16+kx][dh]
  __shared__ unsigned short Vt[32 * VT_STRIDE];    // 14592 B [dh][ky*16+kx]
  __shared__ unsigned short QB[64 * QB_STRIDE];    //  8192 B bias rows (first 4KB = relb transient)

  const int tid = threadIdx.x;
  // XCD-chunked bijective swizzle: 256 tiles = 8 XCDs x 32 contiguous tiles
  const int bid = blockIdx.x;
  const int tile = ((bid & 7) << 5) | (bid >> 3);  // (bid&7)*32 + bid/8
  const int by = tile >> 4, bx = tile & 15;
  const int hd = blockIdx.y, bb = blockIdx.z;
  const size_t pixbase = (size_t)bb * HWPIX;

  const int w = tid >> 6, lane = tid & 63;
  const int g16 = lane >> 4, l15 = lane & 15;
  const int q = w * 16 + l15;
  const int qy = q >> 3, qx = q & 7;
  const int gy = by * BSZ + qy, gx = bx * BSZ + qx;
  const int rot = qx * 4;                          // per-row bank rotation

  // own q fragment (B-operand for both bias and QK MFMAs)
  bf16x8 qf = *(const bf16x8*)(qkv + (pixbase + (size_t)gy * IMG + gx) * MQKV + hd * 96 + g16 * 8);

  // relb -> QB[0..2047] (transient; consumed by bias loads below)
  *(uint4*)(QB + tid * 8) = *(const uint4*)(relb + tid * 8);

  // stage K (rows, b64 pairs) and V (transposed scatter) over padded key space.
  // 224*8 / 256 = 7 exact iterations; pad/OOB keys write zeros (covers all LDS).
  for (int idx = tid; idx < 224 * 8; idx += 256) {
    int key = idx >> 3, part = idx & 7;
    int ky = key >> 4, kx = key & 15;
    int sy = by * BSZ - HALO + ky, sx = bx * BSZ - HALO + kx;
    uint4 val = make_uint4(0,0,0,0);
    if (kx < WIN && (unsigned)sy < (unsigned)IMG && (unsigned)sx < (unsigned)IMG)
      val = *(const uint4*)(qkv + (pixbase + sy * IMG + sx) * MQKV + hd * 96 + 32 + part * 8);
    if (part < 4) {
      unsigned short* kp = Ks + key * KS_STRIDE + part * 8;
      *(unsigned long long*)(kp    ) = (unsigned long long)val.x | ((unsigned long long)val.y << 32);
      *(unsigned long long*)(kp + 4) = (unsigned long long)val.z | ((unsigned long long)val.w << 32);
    } else {
      int dh0 = (part - 4) * 8;
      unsigned int u[4] = {val.x, val.y, val.z, val.w};
      #pragma unroll
      for (int e = 0; e < 4; ++e) {
        Vt[(dh0 + 2*e    ) * VT_STRIDE + key] = (unsigned short)(u[e] & 0xffffu);
        Vt[(dh0 + 2*e + 1) * VT_STRIDE + key] = (unsigned short)(u[e] >> 16);
      }
    }
  }
  __syncthreads();   // staging + relb transient complete

  // ---- bias via MFMA: C[t][q] = rel[t] . q  (rel from QB transient) ----
  {
    const unsigned short* Hb = QB;
    const unsigned short* Wr = QB + 1024;
    bf16x8 ah0 = *(const bf16x8*)(Hb + l15 * 32 + g16 * 8);
    bf16x8 ah1 = *(const bf16x8*)(Hb + (16 + l15) * 32 + g16 * 8);
    bf16x8 aw0 = *(const bf16x8*)(Wr + l15 * 32 + g16 * 8);
    bf16x8 aw1 = *(const bf16x8*)(Wr + (16 + l15) * 32 + g16 * 8);
    __syncthreads();  // ALL lanes' relb reads done before bias writes overwrite QB
    f32x4 z = (f32x4){0.f,0.f,0.f,0.f};
    f32x4 ch0 = __builtin_amdgcn_mfma_f32_16x16x32_bf16(ah0, qf, z, 0, 0, 0);
    f32x4 ch1 = __builtin_amdgcn_mfma_f32_16x16x32_bf16(ah1, qf, z, 0, 0, 0);
    f32x4 cw0 = __builtin_amdgcn_mfma_f32_16x16x32_bf16(aw0, qf, z, 0, 0, 0);
    f32x4 cw1 = __builtin_amdgcn_mfma_f32_16x16x32_bf16(aw1, qf, z, 0, 0, 0);
    unsigned short* QBq = QB + q * QB_STRIDE;
    st_bf4c(QBq +      (( 0 + g16 * 4 + rot) & 31), ch0);
    st_bf4c(QBq +      ((16 + g16 * 4 + rot) & 31), ch1);
    st_bf4c(QBq + 32 + (( 0 + g16 * 4 + rot) & 31), cw0);
    st_bf4c(QBq + 32 + ((16 + g16 * 4 + rot) & 31), cw1);
  }
  __syncthreads();   // bias rows complete (own-wave reads follow; cheap insurance)

  const unsigned short* QBq = QB + q * QB_STRIDE;

  const float LOG2E = 1.4426950408889634f;
  const float SL2E  = SCALE * LOG2E;

  // loop-invariant w-bias (x log2e); pad kx>=14 -> -1e30 masks via exp2->0
  float bw2[4];
  #pragma unroll
  for (int i = 0; i < 4; ++i) {
    int kx = g16 * 4 + i;
    bw2[i] = (kx < WIN) ? bf2f(QBq[32 + ((kx - qx + 13 + rot) & 31)]) * LOG2E : -1e30f;
  }
  const int hbase = 13 - qy + rot;                 // h-region read base (rotated)

  // P-exchange lane map: the 4 lanes sharing q are l15 + 16*{0,1,2,3}
  const int srcA = l15 + ((g16 & 1) ? 32 : 0);     // group 2(g16&1)
  const int srcB = srcA + 16;                      // group 2(g16&1)+1
  const bool hiTile = (g16 >> 1) != 0;

  float lsum = 0.f;
  f32x4 o0 = (f32x4){0.f,0.f,0.f,0.f}, o1 = (f32x4){0.f,0.f,0.f,0.f};
  const f32x4 z = (f32x4){0.f,0.f,0.f,0.f};

  #pragma unroll
  for (int half = 0; half < 2; ++half) {
    unsigned int Plo[7], Phi[7];                   // this half's P tiles, in-register
    #pragma unroll
    for (int u = 0; u < 7; ++u) {
      const int nt = half * 7 + u;                 // == ky of this tile
      bf16x8 kf = ld2(Ks + (nt * 16 + l15) * KS_STRIDE + g16 * 8);
      f32x4 c = __builtin_amdgcn_mfma_f32_16x16x32_bf16(kf, qf, z, 0, 0, 0);
      float bh2 = bf2f(QBq[(nt + hbase) & 31]) * LOG2E; // per-tile-constant h-bias
      float p0 = exp2f(fmaf(c[0], SL2E, bh2 + bw2[0]));
      float p1 = exp2f(fmaf(c[1], SL2E, bh2 + bw2[1]));
      float p2 = exp2f(fmaf(c[2], SL2E, bh2 + bw2[2]));
      float p3 = exp2f(fmaf(c[3], SL2E, bh2 + bw2[3]));
      lsum += (p0 + p1) + (p2 + p3);
      unsigned int plo, phi;                       // asm cvt_pk on VALU values (proven)
      asm("v_cvt_pk_bf16_f32 %0, %1, %2" : "=v"(plo) : "v"(p0), "v"(p1));
      asm("v_cvt_pk_bf16_f32 %0, %1, %2" : "=v"(phi) : "v"(p2), "v"(p3));
      Plo[u] = plo; Phi[u] = phi;
    }
    #pragma unroll
    for (int cc = 0; cc < 4; ++cc) {
      const int ua = 2 * cc;
      const int ub = (cc < 3) ? (2 * cc + 1) : 6;  // cc=3: dummy (masked consumers)
      unsigned int a0 = __shfl(Plo[ua], srcA, 64), a1 = __shfl(Phi[ua], srcA, 64);
      unsigned int b0 = __shfl(Plo[ub], srcA, 64), b1 = __shfl(Phi[ub], srcA, 64);
      unsigned int c0 = __shfl(Plo[ua], srcB, 64), c1 = __shfl(Phi[ua], srcB, 64);
      unsigned int d0 = __shfl(Plo[ub], srcB, 64), d1 = __shfl(Phi[ub], srcB, 64);
      union { unsigned int u32[4]; bf16x8 v; } pfu;
      pfu.u32[0] = hiTile ? b0 : a0;
      pfu.u32[1] = hiTile ? b1 : a1;
      pfu.u32[2] = hiTile ? d0 : c0;
      pfu.u32[3] = hiTile ? d1 : c1;
      bf16x8 pf = pfu.v;
      const bool masked = (cc == 3);               // last 16 keys of half only
      if (masked && g16 >= 2) pf = (bf16x8){0,0,0,0,0,0,0,0};
      int vcol = half * 112 + cc * 32 + g16 * 8;
      if (masked && g16 >= 2) vcol = 0;            // pf==0; keep read in-bounds
      bf16x8 v0 = ld2(Vt + l15 * VT_STRIDE + vcol);
      bf16x8 v1 = ld2(Vt + (16 + l15) * VT_STRIDE + vcol);
      o0 = __builtin_amdgcn_mfma_f32_16x16x32_bf16(v0, pf, o0, 0, 0, 0);
      o1 = __builtin_amdgcn_mfma_f32_16x16x32_bf16(v1, pf, o1, 0, 0, 0);
    }
  }

  lsum += __shfl_xor(lsum, 16);
  lsum += __shfl_xor(lsum, 32);
  float inv = 1.f / lsum;

  float* ob = out + (((size_t)(b0 + bb) * 256 + hd * DH) * HWPIX) + (size_t)gy * IMG + gx;
  #pragma unroll
  for (int i = 0; i < 4; ++i) {
    int dh0 = g16 * 4 + i;
    ob[(size_t)dh0 * HWPIX]        = o0[i] * inv;
    ob[(size_t)(dh0 + 16) * HWPIX] = o1[i] * inv;
  }
}

// ---------------------------------------------------------------------------
extern "C" void kernel_launch(void* const* d_in, const int* in_sizes, int n_in,
                              void* d_out, int out_size, void* d_ws, size_t ws_size,
                              hipStream_t stream)
{
  (void)in_sizes; (void)n_in; (void)out_size;
  const float* x    = (const float*)d_in[0];
  const float* wq   = (const float*)d_in[1];
  const float* wkv  = (const float*)d_in[2];
  const float* hrel = (const float*)d_in[3];
  const float* wrel = (const float*)d_in[4];
  float* out = (float*)d_out;

  const size_t wb_bytes   = (size_t)MQKV * CIN * 2;      // 393216
  const size_t relb_bytes = 4096;
  const size_t qkv_per_b  = (size_t)HWPIX * MQKV * 2;    // 25.2 MB
  const int chunk = (ws_size >= wb_bytes + relb_bytes + 4 * qkv_per_b) ? 4 : 1;

  unsigned short* Wb   = (unsigned short*)d_ws;
  unsigned short* relb = (unsigned short*)((char*)d_ws + wb_bytes);
  unsigned short* qkv  = (unsigned short*)((char*)d_ws + wb_bytes + relb_bytes);

  convw_kernel<<<192, 256, 0, stream>>>(wq, wkv, Wb);
  convrel_kernel<<<8, 256, 0, stream>>>(hrel, wrel, relb);

  for (int b0 = 0; b0 < 4; b0 += chunk) {
    projx_kernel<<<dim3(256, chunk), 256, 0, stream>>>(x + (size_t)b0 * CIN * HWPIX, Wb, qkv);
    attn_kernel<<<dim3(256, HEADS, chunk), 256, 0, stream>>>(qkv, relb, out, b0);
  }
}